// Round 13
// baseline (93.357 us; speedup 1.0000x reference)
//
#include <hip/hip_runtime.h>
#include <cstddef>
#include <cstdint>
#include <math.h>

#define C_IN   512
#define C_TR   64
#define DBINS  59
#define NO     123   // DBINS + C_TR
#define NOP    128   // padded
#define FH     16
#define FW     44
#define NPIX   704
#define NCAM   6
#define NBATCH 2
#define NBN    12
#define NXG    128
#define NYG    128
#define NCH    8     // split-K chunks
#define KCH    (C_IN/NCH)   // 64

// ---- shared tables (both paths) ----
#define WS_CMB     0
#define WS_XS      128
#define WS_YS      176

// ---- fast path layout (floats) ----
#define WSP_PART   256
#define PART_SZ    (NCH*NBN*NPIX*NOP)          // 8,650,752
#define WSP_DEP    (WSP_PART + PART_SZ)
#define DEP_SZ     (NBN*NPIX*C_TR)
#define WSP_CTX    (WSP_DEP + DEP_SZ)
#define WSP_BEV    (WSP_CTX + DEP_SZ)
#define BEV_SZ     (NBATCH*NXG*NYG*C_TR)
#define WS_FAST_TOTALF (WSP_BEV + BEV_SZ)      // ~47.3MB (ws=256MB, fits)

// ---- fallback (R8) layout ----
#define WS_FEAT    256
#define WS_CTX     (WS_FEAT + NBN*NOP*NPIX)
#define WS_BEV     (WS_CTX + NBN*NPIX*C_TR)

__device__ void prep_body(const float* __restrict__ rots,
                          const float* __restrict__ intrins,
                          float* __restrict__ wsf, int t)
{
#pragma clang fp contract(off)
  if (t < NBN) {
    // np.linalg.inv f32 == sgetrf + triangular solve with RECIPROCAL-MULTIPLY
    // (LAPACK pre-inverts the diagonal). 1-ulp vs Cramer-division in inv[0][2]
    // — decides voxel-boundary points (R7 evidence). DO NOT TOUCH.
    const float* K = intrins + t * 9;
    const float* R = rots + t * 9;
    float A[3][3] = {{K[0],K[1],K[2]},{K[3],K[4],K[5]},{K[6],K[7],K[8]}};
    int piv[3] = {0,1,2};
    for (int k = 0; k < 2; ++k) {
      int p = k; float mx = fabsf(A[k][k]);
      for (int r = k+1; r < 3; ++r) { float v = fabsf(A[r][k]); if (v > mx) { mx = v; p = r; } }
      if (p != k) {
        for (int j = 0; j < 3; ++j) { float tmp = A[k][j]; A[k][j] = A[p][j]; A[p][j] = tmp; }
        int ti = piv[k]; piv[k] = piv[p]; piv[p] = ti;
      }
      float rk = 1.0f / A[k][k];
      for (int r = k+1; r < 3; ++r) {
        float l = A[r][k] * rk;
        A[r][k] = l;
        for (int j = k+1; j < 3; ++j) A[r][j] = A[r][j] - l * A[k][j];
      }
    }
    float r0 = 1.0f / A[0][0], r1 = 1.0f / A[1][1], r2 = 1.0f / A[2][2];
    float inv[3][3];
    for (int j = 0; j < 3; ++j) {
      float b0 = (piv[0]==j) ? 1.0f : 0.0f;
      float b1 = (piv[1]==j) ? 1.0f : 0.0f;
      float b2 = (piv[2]==j) ? 1.0f : 0.0f;
      float y0 = b0;
      float y1 = b1 - A[1][0]*y0;
      float y2 = (b2 - A[2][0]*y0) - A[2][1]*y1;
      float x2 = y2 * r2;
      float x1 = (y1 - A[1][2]*x2) * r1;
      float x0 = ((y0 - A[0][1]*x1) - A[0][2]*x2) * r0;
      inv[0][j] = x0; inv[1][j] = x1; inv[2][j] = x2;
    }
    float* cm = wsf + WS_CMB + t * 9;
    #pragma unroll
    for (int i = 0; i < 3; ++i)
      #pragma unroll
      for (int j = 0; j < 3; ++j)
        cm[i*3+j] = (R[i*3+0]*inv[0][j] + R[i*3+1]*inv[1][j]) + R[i*3+2]*inv[2][j];
  }
  if (t < FW) wsf[WS_XS + t] = (t == FW-1) ? 703.0f : (float)((double)t * (703.0 / 43.0));
  if (t < FH) wsf[WS_YS + t] = (t == FH-1) ? 255.0f : (float)((double)t * 17.0);
}

// zero bev + (block 0) build tables — fused to save a dispatch
__global__ __launch_bounds__(256) void zero_prep_kernel(
    float4* __restrict__ bevp, int n4,
    const float* __restrict__ rots, const float* __restrict__ intrins,
    float* __restrict__ wsf)
{
  int i = blockIdx.x * 256 + threadIdx.x;
  const int stride = gridDim.x * 256;
  for (; i < n4; i += stride) bevp[i] = make_float4(0.f, 0.f, 0.f, 0.f);
  if (blockIdx.x == 0 && threadIdx.x < 64)
    prep_body(rots, intrins, wsf, threadIdx.x);
}

// ---------- FAST PATH: split-K GEMM, 8o x 8p per thread ----------
// 64-pixel x 128-output tile, 128 threads. 4 b128 LDS reads per 64 FMAs
// (1 B/FMA — half of the 4x4 tiling). Direct pixel-major epilogue (each
// thread owns 8 consecutive o for 8 consecutive pixels — no LDS transpose).
__global__ __launch_bounds__(128) void gemm_split_kernel(
    const float* __restrict__ x, const float* __restrict__ w,
    float* __restrict__ partial)
{
  __shared__ float Xs[32][64];       // 8 KB
  __shared__ float WsT[32][132];     // 16.9 KB (row 528B, 16-aligned)
  const int bn  = blockIdx.y;
  const int ch  = blockIdx.z;
  const int hw0 = blockIdx.x * 64;
  const int t   = threadIdx.x;       // 0..127
  const int px0 = (t & 7) * 8;       // 8 pixels per thread
  const int oy0 = (t >> 3) * 8;      // 8 outputs per thread (16 groups)
  float acc[8][8] = {};              // [o][p]
  const float* xb = x + (size_t)bn * C_IN * NPIX;
  const int k0c = ch * KCH;

  for (int ks = 0; ks < KCH; ks += 32) {
    const int k0 = k0c + ks;
    #pragma unroll
    for (int i = 0; i < 16; ++i) {   // stage X: 32k x 64p
      int idx = t + i * 128;
      Xs[idx >> 6][idx & 63] = xb[(size_t)(k0 + (idx >> 6)) * NPIX + hw0 + (idx & 63)];
    }
    #pragma unroll
    for (int i = 0; i < 32; ++i) {   // stage W^T: 32k x 128o
      int idx = t + i * 128;
      int o = idx >> 5, k = idx & 31;
      WsT[k][o] = (o < NO) ? w[(size_t)o * C_IN + k0 + k] : 0.0f;
    }
    __syncthreads();
    #pragma unroll
    for (int k = 0; k < 32; ++k) {
      float4 xa = *(const float4*)&Xs[k][px0];
      float4 xc = *(const float4*)&Xs[k][px0 + 4];
      float4 wa = *(const float4*)&WsT[k][oy0];
      float4 wb = *(const float4*)&WsT[k][oy0 + 4];
      float xv[8] = {xa.x,xa.y,xa.z,xa.w,xc.x,xc.y,xc.z,xc.w};
      float wv[8] = {wa.x,wa.y,wa.z,wa.w,wb.x,wb.y,wb.z,wb.w};
      #pragma unroll
      for (int i = 0; i < 8; ++i)
        #pragma unroll
        for (int j = 0; j < 8; ++j)
          acc[i][j] += wv[i] * xv[j];
    }
    __syncthreads();
  }
  float* dst = partial + ((size_t)(ch*NBN + bn) * NPIX + hw0) * NOP;
  #pragma unroll
  for (int j = 0; j < 8; ++j) {
    float4 v0 = make_float4(acc[0][j], acc[1][j], acc[2][j], acc[3][j]);
    float4 v1 = make_float4(acc[4][j], acc[5][j], acc[6][j], acc[7][j]);
    *(float4*)&dst[(size_t)(px0 + j) * NOP + oy0]     = v0;
    *(float4*)&dst[(size_t)(px0 + j) * NOP + oy0 + 4] = v1;
  }
}

// combine partials + bias, in-register softmax, emit depth + ctx (chan-last)
__global__ __launch_bounds__(256) void combine_kernel(
    const float* __restrict__ partial, const float* __restrict__ bias,
    float* __restrict__ depth, float* __restrict__ ctx_t)
{
  const int gid  = (int)((blockIdx.x * blockDim.x + threadIdx.x) >> 6);
  const int lane = threadIdx.x & 63;
  if (gid >= NBN * NPIX) return;
  const int bn  = gid / NPIX;
  const int pix = gid - bn * NPIX;

  float v0 = 0.0f, v1 = 0.0f;
  #pragma unroll
  for (int ch = 0; ch < NCH; ++ch) {
    const float* p = partial + ((size_t)(ch*NBN + bn) * NPIX + pix) * NOP;
    v0 += p[lane];
    v1 += p[lane + 64];
  }
  v0 += bias[lane];
  v1 += (lane + 64 < NO) ? bias[lane + 64] : 0.0f;

  float logit = (lane < DBINS) ? v0 : -__builtin_inff();
  float m = logit;
  #pragma unroll
  for (int off = 32; off; off >>= 1) m = fmaxf(m, __shfl_xor(m, off, 64));
  float e = (lane < DBINS) ? expf(logit - m) : 0.0f;
  float s = e;
  #pragma unroll
  for (int off = 32; off; off >>= 1) s += __shfl_xor(s, off, 64);

  if (lane < DBINS) depth[(size_t)gid * C_TR + lane] = e / s;

  // ctx channel c = lane: value at o = 59 + c.
  // BOTH shuffles unconditional (full exec) — divergent shfl was R9/R10 bug.
  float a  = __shfl(v0, (DBINS + lane) & 63, 64);        // lanes 0..4 use
  float b2 = __shfl(v1, (DBINS + lane - 64) & 63, 64);   // lanes 5..63 use
  float ctxv = (lane < 5) ? a : b2;
  ctx_t[(size_t)gid * C_TR + lane] = ctxv;
}

// One wave per (bn,col,d); 16 rows aggregated in regs -> one 64-lane atomic.
// dep addressing parameterized: addr = dep + bn*sBN + dm1*sD + (r*FW+col)*sP
__global__ __launch_bounds__(256) void agg_kernel(
    const float* __restrict__ wsf, const float* __restrict__ trans,
    const float* __restrict__ dep, const float* __restrict__ ctx,
    float* __restrict__ bev, size_t sBN, size_t sD, size_t sP)
{
#pragma clang fp contract(off)
  const int wid = (int)((blockIdx.x * blockDim.x + threadIdx.x) >> 6);
  const int lane = threadIdx.x & 63;
  if (wid >= NBN * FW * DBINS) return;
  const int bn  = wid / (FW * DBINS);
  const int rem = wid - bn * (FW * DBINS);
  const int col = rem / DBINS;
  const int dm1 = rem - col * DBINS;
  const int b   = bn / NCAM;

  const float* cm = wsf + WS_CMB + bn * 9;
  const float* tr = trans + bn * 3;
  const float dd = 1.0f + (float)dm1;
  const float px = wsf[WS_XS + col] * dd;
  const float py0 = wsf[WS_YS + 0] * dd;
  const float e0 = (cm[0]*px + cm[1]*py0) + cm[2]*dd;
  const float e1 = (cm[3]*px + cm[4]*py0) + cm[5]*dd;
  const float g0 = e0 + tr[0];
  const float g1 = e1 + tr[1];
  const int gx = (int)truncf((g0 + 51.2f) / 0.8f);
  const int gy = (int)truncf((g1 + 51.2f) / 0.8f);
  if (gx < 0 || gx >= NXG || gy < 0 || gy >= NYG) return;

  const int r = lane & 15;
  const float pyr = wsf[WS_YS + r] * dd;
  const float e2 = (cm[6]*px + cm[7]*pyr) + cm[8]*dd;
  const float g2 = e2 + tr[2];
  const int gz = (int)truncf((g2 + 10.0f) / 20.0f);
  unsigned long long mask = __ballot(gz == 0) & 0xFFFFull;
  if (mask == 0) return;

  const float dep_r = dep[(size_t)bn * sBN + (size_t)dm1 * sD + (size_t)(r*FW + col) * sP];
  const float* ctxbase = ctx + ((size_t)bn * NPIX + col) * C_TR + lane;

  float acc = 0.0f;
  #pragma unroll
  for (int row = 0; row < FH; ++row) {
    if ((mask >> row) & 1ull) {    // wave-uniform
      float dv = __shfl(dep_r, row, 64);
      acc += dv * ctxbase[(size_t)(row * FW) * C_TR];
    }
  }
  atomicAdd(&bev[(((size_t)(b*NXG + gx) * NYG + gy) * C_TR) + lane], acc);
}

__global__ __launch_bounds__(256) void transpose_kernel(
    const float* __restrict__ bev, float* __restrict__ out)
{
  __shared__ float tile[NYG][C_TR + 1];
  const int b  = blockIdx.x >> 7;
  const int gx = blockIdx.x & 127;
  const float* src = bev + ((size_t)(b * NXG + gx) * NYG) * C_TR;
  const int t = threadIdx.x;
  #pragma unroll
  for (int i = 0; i < 32; ++i) {
    int idx = t + i * 256;
    tile[idx >> 6][idx & 63] = src[idx];
  }
  __syncthreads();
  const int lane = t & 63;
  const int cw   = t >> 6;
  size_t obase = (size_t)b * (C_TR*NXG*NYG) + (size_t)gx * NYG;
  #pragma unroll
  for (int i = 0; i < 16; ++i) {
    int c = cw + i * 4;
    out[obase + (size_t)c * (NXG*NYG) + lane]      = tile[lane][c];
    out[obase + (size_t)c * (NXG*NYG) + 64 + lane] = tile[64 + lane][c];
  }
}

// ---------- FALLBACK (R8 path, proven): o-major GEMM + in-place softmax ----
__global__ __launch_bounds__(256) void gemm_fb_kernel(
    const float* __restrict__ x, const float* __restrict__ w,
    const float* __restrict__ bias, float* __restrict__ feat,
    float* __restrict__ ctx_t)
{
  __shared__ float Xs[64][32];
  __shared__ float Ws[128][66];
  __shared__ float CtxT[32][C_TR];
  const int bn  = blockIdx.y;
  const int hw0 = blockIdx.x * 32;
  const int t   = threadIdx.x;
  const int tx  = t & 7;
  const int ty  = t >> 3;
  float acc[4][4] = {};
  const float* xb = x + (size_t)bn * C_IN * NPIX;

  for (int k0 = 0; k0 < C_IN; k0 += 64) {
    #pragma unroll
    for (int i = 0; i < 8; ++i) {
      int r = (t >> 5) + i * 8;
      Xs[r][t & 31] = xb[(size_t)(k0 + r) * NPIX + hw0 + (t & 31)];
    }
    #pragma unroll
    for (int i = 0; i < 32; ++i) {
      int o = (t >> 6) + i * 4;
      Ws[o][t & 63] = (o < NO) ? w[(size_t)o * C_IN + k0 + (t & 63)] : 0.0f;
    }
    __syncthreads();
    #pragma unroll 8
    for (int k = 0; k < 64; k += 2) {
      float4 xa = *(const float4*)&Xs[k][tx*4];
      float4 xc = *(const float4*)&Xs[k+1][tx*4];
      #pragma unroll
      for (int i = 0; i < 4; ++i) {
        float2 wv = *(const float2*)&Ws[ty*4+i][k];
        acc[i][0] += wv.x*xa.x; acc[i][1] += wv.x*xa.y;
        acc[i][2] += wv.x*xa.z; acc[i][3] += wv.x*xa.w;
        acc[i][0] += wv.y*xc.x; acc[i][1] += wv.y*xc.y;
        acc[i][2] += wv.y*xc.z; acc[i][3] += wv.y*xc.w;
      }
    }
    __syncthreads();
  }
  #pragma unroll
  for (int i = 0; i < 4; ++i) {
    int o = ty*4 + i;
    float bb = (o < NO) ? bias[o] : 0.0f;
    float4 v = make_float4(acc[i][0]+bb, acc[i][1]+bb, acc[i][2]+bb, acc[i][3]+bb);
    *(float4*)&feat[((size_t)bn * NOP + o) * NPIX + hw0 + tx*4] = v;
    if (o >= DBINS && o < NO) {
      int c = o - DBINS;
      CtxT[tx*4+0][c] = v.x; CtxT[tx*4+1][c] = v.y;
      CtxT[tx*4+2][c] = v.z; CtxT[tx*4+3][c] = v.w;
    }
  }
  __syncthreads();
  const float* src = &CtxT[0][0];
  float* dst = ctx_t + ((size_t)bn * NPIX + hw0) * C_TR;
  #pragma unroll
  for (int k = 0; k < 2; ++k) {
    int f = (t + 256*k) * 4;
    *(float4*)&dst[f] = *(const float4*)&src[f];
  }
}

__global__ __launch_bounds__(256) void softmax_fb_kernel(float* __restrict__ feat)
{
  const int gwid = (int)((blockIdx.x * blockDim.x + threadIdx.x) >> 6);
  const int lane = threadIdx.x & 63;
  if (gwid >= NBN * NPIX) return;
  const int bn = gwid / NPIX;
  const int hw = gwid - bn * NPIX;
  float* fb = feat + (size_t)bn * NOP * NPIX + hw;
  float logit = (lane < DBINS) ? fb[(size_t)lane * NPIX] : -__builtin_inff();
  float m = logit;
  #pragma unroll
  for (int off = 32; off; off >>= 1) m = fmaxf(m, __shfl_xor(m, off, 64));
  float e = (lane < DBINS) ? expf(logit - m) : 0.0f;
  float s = e;
  #pragma unroll
  for (int off = 32; off; off >>= 1) s += __shfl_xor(s, off, 64);
  if (lane < DBINS) fb[(size_t)lane * NPIX] = e / s;
}

extern "C" void kernel_launch(void* const* d_in, const int* in_sizes, int n_in,
                              void* d_out, int out_size, void* d_ws, size_t ws_size,
                              hipStream_t stream)
{
  const float* x       = (const float*)d_in[0];
  const float* rots    = (const float*)d_in[1];
  const float* trans   = (const float*)d_in[2];
  const float* intrins = (const float*)d_in[3];
  const float* wd      = (const float*)d_in[4];
  const float* bd      = (const float*)d_in[5];
  float* out = (float*)d_out;
  float* wsf = (float*)d_ws;

  if (ws_size >= (size_t)WS_FAST_TOTALF * sizeof(float)) {
    float* part  = wsf + WSP_PART;
    float* depth = wsf + WSP_DEP;
    float* ctx_t = wsf + WSP_CTX;
    float* bev   = wsf + WSP_BEV;
    zero_prep_kernel<<<2048, 256, 0, stream>>>((float4*)bev, BEV_SZ/4, rots, intrins, wsf);
    gemm_split_kernel<<<dim3(NPIX/64, NBN, NCH), 128, 0, stream>>>(x, wd, part);
    combine_kernel<<<(NBN*NPIX)/4, 256, 0, stream>>>(part, bd, depth, ctx_t);
    agg_kernel<<<(NBN*FW*DBINS + 3)/4, 256, 0, stream>>>(
        wsf, trans, depth, ctx_t, bev,
        (size_t)NPIX * C_TR, (size_t)1, (size_t)C_TR);
    transpose_kernel<<<NBATCH*NXG, 256, 0, stream>>>(bev, out);
  } else {
    float* feat  = wsf + WS_FEAT;
    float* ctx_t = wsf + WS_CTX;
    float* bev   = wsf + WS_BEV;
    zero_prep_kernel<<<2048, 256, 0, stream>>>((float4*)bev, BEV_SZ/4, rots, intrins, wsf);
    gemm_fb_kernel<<<dim3(NPIX/32, NBN), 256, 0, stream>>>(x, wd, bd, feat, ctx_t);
    softmax_fb_kernel<<<(NBN*NPIX)/4, 256, 0, stream>>>(feat);
    agg_kernel<<<(NBN*FW*DBINS + 3)/4, 256, 0, stream>>>(
        wsf, trans, feat, ctx_t, bev,
        (size_t)NOP * NPIX, (size_t)NPIX, (size_t)1);
    transpose_kernel<<<NBATCH*NXG, 256, 0, stream>>>(bev, out);
  }
}

// Round 14
// 88.254 us; speedup vs baseline: 1.0578x; 1.0578x over previous
//
#include <hip/hip_runtime.h>
#include <cstddef>
#include <cstdint>
#include <math.h>

#define C_IN   512
#define C_TR   64
#define DBINS  59
#define NO     123   // DBINS + C_TR
#define NOP    128   // padded
#define FH     16
#define FW     44
#define NPIX   704
#define NCAM   6
#define NBATCH 2
#define NBN    12
#define NXG    128
#define NYG    128
#define NCH    8     // split-K chunks
#define KCH    (C_IN/NCH)   // 64

// ---- shared tables (both paths) ----
#define WS_CMB     0
#define WS_XS      128
#define WS_YS      176

// ---- fast path layout (floats) ----
#define WSP_PART   256
#define PART_SZ    (NCH*NBN*NPIX*NOP)          // 8,650,752
#define WSP_DEP    (WSP_PART + PART_SZ)
#define DEP_SZ     (NBN*NPIX*C_TR)
#define WSP_CTX    (WSP_DEP + DEP_SZ)
#define WSP_BEV    (WSP_CTX + DEP_SZ)
#define BEV_SZ     (NBATCH*NXG*NYG*C_TR)
#define WS_FAST_TOTALF (WSP_BEV + BEV_SZ)      // ~47.3MB (ws=256MB, fits)

// ---- fallback (R8) layout ----
#define WS_FEAT    256
#define WS_CTX     (WS_FEAT + NBN*NOP*NPIX)
#define WS_BEV     (WS_CTX + NBN*NPIX*C_TR)

__device__ void prep_body(const float* __restrict__ rots,
                          const float* __restrict__ intrins,
                          float* __restrict__ wsf, int t)
{
#pragma clang fp contract(off)
  if (t < NBN) {
    // np.linalg.inv f32 == sgetrf + triangular solve with RECIPROCAL-MULTIPLY
    // (LAPACK pre-inverts the diagonal). 1-ulp vs Cramer-division in inv[0][2]
    // — decides voxel-boundary points (R7 evidence). DO NOT TOUCH.
    const float* K = intrins + t * 9;
    const float* R = rots + t * 9;
    float A[3][3] = {{K[0],K[1],K[2]},{K[3],K[4],K[5]},{K[6],K[7],K[8]}};
    int piv[3] = {0,1,2};
    for (int k = 0; k < 2; ++k) {
      int p = k; float mx = fabsf(A[k][k]);
      for (int r = k+1; r < 3; ++r) { float v = fabsf(A[r][k]); if (v > mx) { mx = v; p = r; } }
      if (p != k) {
        for (int j = 0; j < 3; ++j) { float tmp = A[k][j]; A[k][j] = A[p][j]; A[p][j] = tmp; }
        int ti = piv[k]; piv[k] = piv[p]; piv[p] = ti;
      }
      float rk = 1.0f / A[k][k];
      for (int r = k+1; r < 3; ++r) {
        float l = A[r][k] * rk;
        A[r][k] = l;
        for (int j = k+1; j < 3; ++j) A[r][j] = A[r][j] - l * A[k][j];
      }
    }
    float r0 = 1.0f / A[0][0], r1 = 1.0f / A[1][1], r2 = 1.0f / A[2][2];
    float inv[3][3];
    for (int j = 0; j < 3; ++j) {
      float b0 = (piv[0]==j) ? 1.0f : 0.0f;
      float b1 = (piv[1]==j) ? 1.0f : 0.0f;
      float b2 = (piv[2]==j) ? 1.0f : 0.0f;
      float y0 = b0;
      float y1 = b1 - A[1][0]*y0;
      float y2 = (b2 - A[2][0]*y0) - A[2][1]*y1;
      float x2 = y2 * r2;
      float x1 = (y1 - A[1][2]*x2) * r1;
      float x0 = ((y0 - A[0][1]*x1) - A[0][2]*x2) * r0;
      inv[0][j] = x0; inv[1][j] = x1; inv[2][j] = x2;
    }
    float* cm = wsf + WS_CMB + t * 9;
    #pragma unroll
    for (int i = 0; i < 3; ++i)
      #pragma unroll
      for (int j = 0; j < 3; ++j)
        cm[i*3+j] = (R[i*3+0]*inv[0][j] + R[i*3+1]*inv[1][j]) + R[i*3+2]*inv[2][j];
  }
  if (t < FW) wsf[WS_XS + t] = (t == FW-1) ? 703.0f : (float)((double)t * (703.0 / 43.0));
  if (t < FH) wsf[WS_YS + t] = (t == FH-1) ? 255.0f : (float)((double)t * 17.0);
}

// zero bev + (block 0) build tables — fused to save a dispatch
__global__ __launch_bounds__(256) void zero_prep_kernel(
    float4* __restrict__ bevp, int n4,
    const float* __restrict__ rots, const float* __restrict__ intrins,
    float* __restrict__ wsf)
{
  int i = blockIdx.x * 256 + threadIdx.x;
  const int stride = gridDim.x * 256;
  for (; i < n4; i += stride) bevp[i] = make_float4(0.f, 0.f, 0.f, 0.f);
  if (blockIdx.x == 0 && threadIdx.x < 64)
    prep_body(rots, intrins, wsf, threadIdx.x);
}

// ---------- FAST PATH: split-K GEMM (R12-proven body, NCH=8) ----------
__global__ __launch_bounds__(256) void gemm_split_kernel(
    const float* __restrict__ x, const float* __restrict__ w,
    float* __restrict__ partial)
{
  __shared__ float smem[1024 + 32*132];            // 21 KB
  float (*Xs)[32]   = (float(*)[32])smem;          // [32 k][32 pix]
  float (*WsT)[132] = (float(*)[132])(smem + 1024);// [32 k][128 o +pad4]
  const int bn  = blockIdx.y;
  const int ch  = blockIdx.z;
  const int hw0 = blockIdx.x * 32;
  const int t   = threadIdx.x;
  const int tx  = t & 7;     // pixel quad
  const int ty  = t >> 3;    // output quad (0..31)
  float acc[4][4] = {};      // [o_i][pix_j]
  const float* xb = x + (size_t)bn * C_IN * NPIX;
  const int k0c = ch * KCH;

  for (int ks = 0; ks < KCH; ks += 32) {
    const int k0 = k0c + ks;
    #pragma unroll
    for (int i = 0; i < 4; ++i) {
      int k = (t >> 5) + i * 8;
      Xs[k][t & 31] = xb[(size_t)(k0 + k) * NPIX + hw0 + (t & 31)];
    }
    #pragma unroll
    for (int i = 0; i < 16; ++i) {
      int o = (t >> 5) + i * 8;
      WsT[t & 31][o] = (o < NO) ? w[(size_t)o * C_IN + k0 + (t & 31)] : 0.0f;
    }
    __syncthreads();
    #pragma unroll
    for (int k = 0; k < 32; ++k) {
      float4 xa = *(const float4*)&Xs[k][tx*4];
      float4 wv = *(const float4*)&WsT[k][ty*4];
      acc[0][0] += wv.x*xa.x; acc[0][1] += wv.x*xa.y; acc[0][2] += wv.x*xa.z; acc[0][3] += wv.x*xa.w;
      acc[1][0] += wv.y*xa.x; acc[1][1] += wv.y*xa.y; acc[1][2] += wv.y*xa.z; acc[1][3] += wv.y*xa.w;
      acc[2][0] += wv.z*xa.x; acc[2][1] += wv.z*xa.y; acc[2][2] += wv.z*xa.z; acc[2][3] += wv.z*xa.w;
      acc[3][0] += wv.w*xa.x; acc[3][1] += wv.w*xa.y; acc[3][2] += wv.w*xa.z; acc[3][3] += wv.w*xa.w;
    }
    __syncthreads();
  }
  // epilogue: transpose to pixel-major via LDS, coalesced global write
  float (*PT)[128] = (float(*)[128])smem;          // [32 pix][128 o] aligned
  #pragma unroll
  for (int j = 0; j < 4; ++j) {
    float4 v = make_float4(acc[0][j], acc[1][j], acc[2][j], acc[3][j]);
    *(float4*)&PT[tx*4 + j][ty*4] = v;
  }
  __syncthreads();
  float* dst = partial + ((size_t)(ch*NBN + bn) * NPIX + hw0) * NOP;
  #pragma unroll
  for (int p = 0; p < 4; ++p) {
    int pix = (t >> 5) + p * 8;
    int o4  = (t & 31) * 4;
    *(float4*)&dst[(size_t)pix * NOP + o4] = *(const float4*)&PT[pix][o4];
  }
}

// combine partials + bias, in-register softmax, emit depth + ctx (chan-last)
__global__ __launch_bounds__(256) void combine_kernel(
    const float* __restrict__ partial, const float* __restrict__ bias,
    float* __restrict__ depth, float* __restrict__ ctx_t)
{
  const int gid  = (int)((blockIdx.x * blockDim.x + threadIdx.x) >> 6);
  const int lane = threadIdx.x & 63;
  if (gid >= NBN * NPIX) return;
  const int bn  = gid / NPIX;
  const int pix = gid - bn * NPIX;

  float v0 = 0.0f, v1 = 0.0f;
  #pragma unroll
  for (int ch = 0; ch < NCH; ++ch) {
    const float* p = partial + ((size_t)(ch*NBN + bn) * NPIX + pix) * NOP;
    v0 += p[lane];
    v1 += p[lane + 64];
  }
  v0 += bias[lane];
  v1 += (lane + 64 < NO) ? bias[lane + 64] : 0.0f;

  float logit = (lane < DBINS) ? v0 : -__builtin_inff();
  float m = logit;
  #pragma unroll
  for (int off = 32; off; off >>= 1) m = fmaxf(m, __shfl_xor(m, off, 64));
  float e = (lane < DBINS) ? expf(logit - m) : 0.0f;
  float s = e;
  #pragma unroll
  for (int off = 32; off; off >>= 1) s += __shfl_xor(s, off, 64);

  if (lane < DBINS) depth[(size_t)gid * C_TR + lane] = e / s;

  // ctx channel c = lane: value at o = 59 + c.
  // BOTH shuffles unconditional (full exec) — divergent shfl was R9/R10 bug.
  float a  = __shfl(v0, (DBINS + lane) & 63, 64);        // lanes 0..4 use
  float b2 = __shfl(v1, (DBINS + lane - 64) & 63, 64);   // lanes 5..63 use
  float ctxv = (lane < 5) ? a : b2;
  ctx_t[(size_t)gid * C_TR + lane] = ctxv;
}

// One wave per (bn,col,d); 16 rows aggregated in regs -> one 64-lane atomic.
// dep addressing parameterized: addr = dep + bn*sBN + dm1*sD + (r*FW+col)*sP
__global__ __launch_bounds__(256) void agg_kernel(
    const float* __restrict__ wsf, const float* __restrict__ trans,
    const float* __restrict__ dep, const float* __restrict__ ctx,
    float* __restrict__ bev, size_t sBN, size_t sD, size_t sP)
{
#pragma clang fp contract(off)
  const int wid = (int)((blockIdx.x * blockDim.x + threadIdx.x) >> 6);
  const int lane = threadIdx.x & 63;
  if (wid >= NBN * FW * DBINS) return;
  const int bn  = wid / (FW * DBINS);
  const int rem = wid - bn * (FW * DBINS);
  const int col = rem / DBINS;
  const int dm1 = rem - col * DBINS;
  const int b   = bn / NCAM;

  const float* cm = wsf + WS_CMB + bn * 9;
  const float* tr = trans + bn * 3;
  const float dd = 1.0f + (float)dm1;
  const float px = wsf[WS_XS + col] * dd;
  const float py0 = wsf[WS_YS + 0] * dd;
  const float e0 = (cm[0]*px + cm[1]*py0) + cm[2]*dd;
  const float e1 = (cm[3]*px + cm[4]*py0) + cm[5]*dd;
  const float g0 = e0 + tr[0];
  const float g1 = e1 + tr[1];
  const int gx = (int)truncf((g0 + 51.2f) / 0.8f);
  const int gy = (int)truncf((g1 + 51.2f) / 0.8f);
  if (gx < 0 || gx >= NXG || gy < 0 || gy >= NYG) return;

  const int r = lane & 15;
  const float pyr = wsf[WS_YS + r] * dd;
  const float e2 = (cm[6]*px + cm[7]*pyr) + cm[8]*dd;
  const float g2 = e2 + tr[2];
  const int gz = (int)truncf((g2 + 10.0f) / 20.0f);
  unsigned long long mask = __ballot(gz == 0) & 0xFFFFull;
  if (mask == 0) return;

  const float dep_r = dep[(size_t)bn * sBN + (size_t)dm1 * sD + (size_t)(r*FW + col) * sP];
  const float* ctxbase = ctx + ((size_t)bn * NPIX + col) * C_TR + lane;

  float acc = 0.0f;
  #pragma unroll
  for (int row = 0; row < FH; ++row) {
    if ((mask >> row) & 1ull) {    // wave-uniform
      float dv = __shfl(dep_r, row, 64);
      acc += dv * ctxbase[(size_t)(row * FW) * C_TR];
    }
  }
  atomicAdd(&bev[(((size_t)(b*NXG + gx) * NYG + gy) * C_TR) + lane], acc);
}

__global__ __launch_bounds__(256) void transpose_kernel(
    const float* __restrict__ bev, float* __restrict__ out)
{
  __shared__ float tile[NYG][C_TR + 1];
  const int b  = blockIdx.x >> 7;
  const int gx = blockIdx.x & 127;
  const float* src = bev + ((size_t)(b * NXG + gx) * NYG) * C_TR;
  const int t = threadIdx.x;
  #pragma unroll
  for (int i = 0; i < 32; ++i) {
    int idx = t + i * 256;
    tile[idx >> 6][idx & 63] = src[idx];
  }
  __syncthreads();
  const int lane = t & 63;
  const int cw   = t >> 6;
  size_t obase = (size_t)b * (C_TR*NXG*NYG) + (size_t)gx * NYG;
  #pragma unroll
  for (int i = 0; i < 16; ++i) {
    int c = cw + i * 4;
    out[obase + (size_t)c * (NXG*NYG) + lane]      = tile[lane][c];
    out[obase + (size_t)c * (NXG*NYG) + 64 + lane] = tile[64 + lane][c];
  }
}

// ---------- FALLBACK (R8 path, proven): o-major GEMM + in-place softmax ----
__global__ __launch_bounds__(256) void gemm_fb_kernel(
    const float* __restrict__ x, const float* __restrict__ w,
    const float* __restrict__ bias, float* __restrict__ feat,
    float* __restrict__ ctx_t)
{
  __shared__ float Xs[64][32];
  __shared__ float Ws[128][66];
  __shared__ float CtxT[32][C_TR];
  const int bn  = blockIdx.y;
  const int hw0 = blockIdx.x * 32;
  const int t   = threadIdx.x;
  const int tx  = t & 7;
  const int ty  = t >> 3;
  float acc[4][4] = {};
  const float* xb = x + (size_t)bn * C_IN * NPIX;

  for (int k0 = 0; k0 < C_IN; k0 += 64) {
    #pragma unroll
    for (int i = 0; i < 8; ++i) {
      int r = (t >> 5) + i * 8;
      Xs[r][t & 31] = xb[(size_t)(k0 + r) * NPIX + hw0 + (t & 31)];
    }
    #pragma unroll
    for (int i = 0; i < 32; ++i) {
      int o = (t >> 6) + i * 4;
      Ws[o][t & 63] = (o < NO) ? w[(size_t)o * C_IN + k0 + (t & 63)] : 0.0f;
    }
    __syncthreads();
    #pragma unroll 8
    for (int k = 0; k < 64; k += 2) {
      float4 xa = *(const float4*)&Xs[k][tx*4];
      float4 xc = *(const float4*)&Xs[k+1][tx*4];
      #pragma unroll
      for (int i = 0; i < 4; ++i) {
        float2 wv = *(const float2*)&Ws[ty*4+i][k];
        acc[i][0] += wv.x*xa.x; acc[i][1] += wv.x*xa.y;
        acc[i][2] += wv.x*xa.z; acc[i][3] += wv.x*xa.w;
        acc[i][0] += wv.y*xc.x; acc[i][1] += wv.y*xc.y;
        acc[i][2] += wv.y*xc.z; acc[i][3] += wv.y*xc.w;
      }
    }
    __syncthreads();
  }
  #pragma unroll
  for (int i = 0; i < 4; ++i) {
    int o = ty*4 + i;
    float bb = (o < NO) ? bias[o] : 0.0f;
    float4 v = make_float4(acc[i][0]+bb, acc[i][1]+bb, acc[i][2]+bb, acc[i][3]+bb);
    *(float4*)&feat[((size_t)bn * NOP + o) * NPIX + hw0 + tx*4] = v;
    if (o >= DBINS && o < NO) {
      int c = o - DBINS;
      CtxT[tx*4+0][c] = v.x; CtxT[tx*4+1][c] = v.y;
      CtxT[tx*4+2][c] = v.z; CtxT[tx*4+3][c] = v.w;
    }
  }
  __syncthreads();
  const float* src = &CtxT[0][0];
  float* dst = ctx_t + ((size_t)bn * NPIX + hw0) * C_TR;
  #pragma unroll
  for (int k = 0; k < 2; ++k) {
    int f = (t + 256*k) * 4;
    *(float4*)&dst[f] = *(const float4*)&src[f];
  }
}

__global__ __launch_bounds__(256) void softmax_fb_kernel(float* __restrict__ feat)
{
  const int gwid = (int)((blockIdx.x * blockDim.x + threadIdx.x) >> 6);
  const int lane = threadIdx.x & 63;
  if (gwid >= NBN * NPIX) return;
  const int bn = gwid / NPIX;
  const int hw = gwid - bn * NPIX;
  float* fb = feat + (size_t)bn * NOP * NPIX + hw;
  float logit = (lane < DBINS) ? fb[(size_t)lane * NPIX] : -__builtin_inff();
  float m = logit;
  #pragma unroll
  for (int off = 32; off; off >>= 1) m = fmaxf(m, __shfl_xor(m, off, 64));
  float e = (lane < DBINS) ? expf(logit - m) : 0.0f;
  float s = e;
  #pragma unroll
  for (int off = 32; off; off >>= 1) s += __shfl_xor(s, off, 64);
  if (lane < DBINS) fb[(size_t)lane * NPIX] = e / s;
}

extern "C" void kernel_launch(void* const* d_in, const int* in_sizes, int n_in,
                              void* d_out, int out_size, void* d_ws, size_t ws_size,
                              hipStream_t stream)
{
  const float* x       = (const float*)d_in[0];
  const float* rots    = (const float*)d_in[1];
  const float* trans   = (const float*)d_in[2];
  const float* intrins = (const float*)d_in[3];
  const float* wd      = (const float*)d_in[4];
  const float* bd      = (const float*)d_in[5];
  float* out = (float*)d_out;
  float* wsf = (float*)d_ws;

  if (ws_size >= (size_t)WS_FAST_TOTALF * sizeof(float)) {
    float* part  = wsf + WSP_PART;
    float* depth = wsf + WSP_DEP;
    float* ctx_t = wsf + WSP_CTX;
    float* bev   = wsf + WSP_BEV;
    zero_prep_kernel<<<2048, 256, 0, stream>>>((float4*)bev, BEV_SZ/4, rots, intrins, wsf);
    gemm_split_kernel<<<dim3(NPIX/32, NBN, NCH), 256, 0, stream>>>(x, wd, part);
    combine_kernel<<<(NBN*NPIX)/4, 256, 0, stream>>>(part, bd, depth, ctx_t);
    agg_kernel<<<(NBN*FW*DBINS + 3)/4, 256, 0, stream>>>(
        wsf, trans, depth, ctx_t, bev,
        (size_t)NPIX * C_TR, (size_t)1, (size_t)C_TR);
    transpose_kernel<<<NBATCH*NXG, 256, 0, stream>>>(bev, out);
  } else {
    float* feat  = wsf + WS_FEAT;
    float* ctx_t = wsf + WS_CTX;
    float* bev   = wsf + WS_BEV;
    zero_prep_kernel<<<2048, 256, 0, stream>>>((float4*)bev, BEV_SZ/4, rots, intrins, wsf);
    gemm_fb_kernel<<<dim3(NPIX/32, NBN), 256, 0, stream>>>(x, wd, bd, feat, ctx_t);
    softmax_fb_kernel<<<(NBN*NPIX)/4, 256, 0, stream>>>(feat);
    agg_kernel<<<(NBN*FW*DBINS + 3)/4, 256, 0, stream>>>(
        wsf, trans, feat, ctx_t, bev,
        (size_t)NOP * NPIX, (size_t)NPIX, (size_t)1);
    transpose_kernel<<<NBATCH*NXG, 256, 0, stream>>>(bev, out);
  }
}

// Round 15
// 80.070 us; speedup vs baseline: 1.1659x; 1.1022x over previous
//
#include <hip/hip_runtime.h>
#include <cstddef>
#include <cstdint>
#include <math.h>

#define C_IN   512
#define C_TR   64
#define DBINS  59
#define NO     123   // DBINS + C_TR
#define NOP    128   // padded
#define FH     16
#define FW     44
#define NPIX   704
#define NCAM   6
#define NBATCH 2
#define NBN    12
#define NXG    128
#define NYG    128
#define NCH    8     // split-K chunks
#define KCH    (C_IN/NCH)   // 64

// ---- shared tables (both paths) ----
#define WS_CMB     0
#define WS_XS      128
#define WS_YS      176

// ---- fast path layout (floats) ----
#define WSP_WT     256
#define WT_SZ      (C_IN*NOP)                  // 65,536
#define WSP_PART   (WSP_WT + WT_SZ)
#define PART_SZ    (NCH*NBN*NPIX*NOP)          // 8,650,752
#define WSP_DEP    (WSP_PART + PART_SZ)
#define DEP_SZ     (NBN*NPIX*C_TR)
#define WSP_CTX    (WSP_DEP + DEP_SZ)
#define WSP_BEV    (WSP_CTX + DEP_SZ)
#define BEV_SZ     (NBATCH*NXG*NYG*C_TR)
#define WS_FAST_TOTALF (WSP_BEV + BEV_SZ)      // ~47.6MB (ws=256MB, fits)

// ---- fallback (R8) layout ----
#define WS_FEAT    256
#define WS_CTX     (WS_FEAT + NBN*NOP*NPIX)
#define WS_BEV     (WS_CTX + NBN*NPIX*C_TR)

__device__ void prep_body(const float* __restrict__ rots,
                          const float* __restrict__ intrins,
                          float* __restrict__ wsf, int t)
{
#pragma clang fp contract(off)
  if (t < NBN) {
    // np.linalg.inv f32 == sgetrf + triangular solve with RECIPROCAL-MULTIPLY
    // (LAPACK pre-inverts the diagonal). 1-ulp vs Cramer-division in inv[0][2]
    // — decides voxel-boundary points (R7 evidence). DO NOT TOUCH.
    const float* K = intrins + t * 9;
    const float* R = rots + t * 9;
    float A[3][3] = {{K[0],K[1],K[2]},{K[3],K[4],K[5]},{K[6],K[7],K[8]}};
    int piv[3] = {0,1,2};
    for (int k = 0; k < 2; ++k) {
      int p = k; float mx = fabsf(A[k][k]);
      for (int r = k+1; r < 3; ++r) { float v = fabsf(A[r][k]); if (v > mx) { mx = v; p = r; } }
      if (p != k) {
        for (int j = 0; j < 3; ++j) { float tmp = A[k][j]; A[k][j] = A[p][j]; A[p][j] = tmp; }
        int ti = piv[k]; piv[k] = piv[p]; piv[p] = ti;
      }
      float rk = 1.0f / A[k][k];
      for (int r = k+1; r < 3; ++r) {
        float l = A[r][k] * rk;
        A[r][k] = l;
        for (int j = k+1; j < 3; ++j) A[r][j] = A[r][j] - l * A[k][j];
      }
    }
    float r0 = 1.0f / A[0][0], r1 = 1.0f / A[1][1], r2 = 1.0f / A[2][2];
    float inv[3][3];
    for (int j = 0; j < 3; ++j) {
      float b0 = (piv[0]==j) ? 1.0f : 0.0f;
      float b1 = (piv[1]==j) ? 1.0f : 0.0f;
      float b2 = (piv[2]==j) ? 1.0f : 0.0f;
      float y0 = b0;
      float y1 = b1 - A[1][0]*y0;
      float y2 = (b2 - A[2][0]*y0) - A[2][1]*y1;
      float x2 = y2 * r2;
      float x1 = (y1 - A[1][2]*x2) * r1;
      float x0 = ((y0 - A[0][1]*x1) - A[0][2]*x2) * r0;
      inv[0][j] = x0; inv[1][j] = x1; inv[2][j] = x2;
    }
    float* cm = wsf + WS_CMB + t * 9;
    #pragma unroll
    for (int i = 0; i < 3; ++i)
      #pragma unroll
      for (int j = 0; j < 3; ++j)
        cm[i*3+j] = (R[i*3+0]*inv[0][j] + R[i*3+1]*inv[1][j]) + R[i*3+2]*inv[2][j];
  }
  if (t < FW) wsf[WS_XS + t] = (t == FW-1) ? 703.0f : (float)((double)t * (703.0 / 43.0));
  if (t < FH) wsf[WS_YS + t] = (t == FH-1) ? 255.0f : (float)((double)t * 17.0);
}

// zero bev + transpose W to k-major (wT, L2-resident) + (block 0) tables
__global__ __launch_bounds__(256) void zero_prep_kernel(
    float4* __restrict__ bevp, int n4,
    const float* __restrict__ rots, const float* __restrict__ intrins,
    const float* __restrict__ w, float* __restrict__ wT,
    float* __restrict__ wsf)
{
  int i = blockIdx.x * 256 + threadIdx.x;
  const int stride = gridDim.x * 256;
  for (int j = i; j < n4; j += stride) bevp[j] = make_float4(0.f, 0.f, 0.f, 0.f);
  if (wT) {
    for (int j = i; j < C_IN * NOP; j += stride) {
      int k = j >> 7, o = j & 127;               // coalesced wT write
      wT[j] = (o < NO) ? w[(size_t)o * C_IN + k] : 0.0f;
    }
  }
  if (blockIdx.x == 0 && threadIdx.x < 64)
    prep_body(rots, intrins, wsf, threadIdx.x);
}

// ---------- FAST PATH: split-K GEMM; W from global (L2), X from LDS ----------
__global__ __launch_bounds__(256) void gemm_split_kernel(
    const float* __restrict__ x, const float* __restrict__ wT,
    float* __restrict__ partial)
{
  __shared__ float smem[32 * 128];                 // 16 KB (Xs + PT epilogue)
  float (*Xs)[32] = (float(*)[32])smem;            // [32 k][32 pix]
  const int bn  = blockIdx.y;
  const int ch  = blockIdx.z;
  const int hw0 = blockIdx.x * 32;
  const int t   = threadIdx.x;
  const int tx  = t & 7;     // pixel quad
  const int ty  = t >> 3;    // output quad (0..31)
  float acc[4][4] = {};      // [o_i][pix_j]
  const float* xb = x + (size_t)bn * C_IN * NPIX;
  const int k0c = ch * KCH;

  for (int ks = 0; ks < KCH; ks += 32) {
    const int k0 = k0c + ks;
    #pragma unroll
    for (int i = 0; i < 4; ++i) {
      int k = (t >> 5) + i * 8;
      Xs[k][t & 31] = xb[(size_t)(k0 + k) * NPIX + hw0 + (t & 31)];
    }
    __syncthreads();
    const float4* wp = (const float4*)(wT + (size_t)k0 * NOP) + ty;  // stride 32 float4/row
    #pragma unroll 8
    for (int k = 0; k < 32; ++k) {
      float4 xa = *(const float4*)&Xs[k][tx*4];
      float4 wv = wp[k * 32];                      // global b128, L2-hit
      acc[0][0] += wv.x*xa.x; acc[0][1] += wv.x*xa.y; acc[0][2] += wv.x*xa.z; acc[0][3] += wv.x*xa.w;
      acc[1][0] += wv.y*xa.x; acc[1][1] += wv.y*xa.y; acc[1][2] += wv.y*xa.z; acc[1][3] += wv.y*xa.w;
      acc[2][0] += wv.z*xa.x; acc[2][1] += wv.z*xa.y; acc[2][2] += wv.z*xa.z; acc[2][3] += wv.z*xa.w;
      acc[3][0] += wv.w*xa.x; acc[3][1] += wv.w*xa.y; acc[3][2] += wv.w*xa.z; acc[3][3] += wv.w*xa.w;
    }
    __syncthreads();
  }
  // epilogue: transpose to pixel-major via LDS, coalesced global write
  float (*PT)[128] = (float(*)[128])smem;          // [32 pix][128 o] aligned
  #pragma unroll
  for (int j = 0; j < 4; ++j) {
    float4 v = make_float4(acc[0][j], acc[1][j], acc[2][j], acc[3][j]);
    *(float4*)&PT[tx*4 + j][ty*4] = v;
  }
  __syncthreads();
  float* dst = partial + ((size_t)(ch*NBN + bn) * NPIX + hw0) * NOP;
  #pragma unroll
  for (int p = 0; p < 4; ++p) {
    int pix = (t >> 5) + p * 8;
    int o4  = (t & 31) * 4;
    *(float4*)&dst[(size_t)pix * NOP + o4] = *(const float4*)&PT[pix][o4];
  }
}

// combine partials + bias, in-register softmax, emit depth + ctx (chan-last)
__global__ __launch_bounds__(256) void combine_kernel(
    const float* __restrict__ partial, const float* __restrict__ bias,
    float* __restrict__ depth, float* __restrict__ ctx_t)
{
  const int gid  = (int)((blockIdx.x * blockDim.x + threadIdx.x) >> 6);
  const int lane = threadIdx.x & 63;
  if (gid >= NBN * NPIX) return;
  const int bn  = gid / NPIX;
  const int pix = gid - bn * NPIX;

  float v0 = 0.0f, v1 = 0.0f;
  #pragma unroll
  for (int ch = 0; ch < NCH; ++ch) {
    const float* p = partial + ((size_t)(ch*NBN + bn) * NPIX + pix) * NOP;
    v0 += p[lane];
    v1 += p[lane + 64];
  }
  v0 += bias[lane];
  v1 += (lane + 64 < NO) ? bias[lane + 64] : 0.0f;

  float logit = (lane < DBINS) ? v0 : -__builtin_inff();
  float m = logit;
  #pragma unroll
  for (int off = 32; off; off >>= 1) m = fmaxf(m, __shfl_xor(m, off, 64));
  float e = (lane < DBINS) ? expf(logit - m) : 0.0f;
  float s = e;
  #pragma unroll
  for (int off = 32; off; off >>= 1) s += __shfl_xor(s, off, 64);

  if (lane < DBINS) depth[(size_t)gid * C_TR + lane] = e / s;

  // ctx channel c = lane: value at o = 59 + c.
  // BOTH shuffles unconditional (full exec) — divergent shfl was R9/R10 bug.
  float a  = __shfl(v0, (DBINS + lane) & 63, 64);        // lanes 0..4 use
  float b2 = __shfl(v1, (DBINS + lane - 64) & 63, 64);   // lanes 5..63 use
  float ctxv = (lane < 5) ? a : b2;
  ctx_t[(size_t)gid * C_TR + lane] = ctxv;
}

// One wave per (bn,col,d); 16 rows aggregated in regs -> one 64-lane atomic.
__global__ __launch_bounds__(256) void agg_kernel(
    const float* __restrict__ wsf, const float* __restrict__ trans,
    const float* __restrict__ dep, const float* __restrict__ ctx,
    float* __restrict__ bev, size_t sBN, size_t sD, size_t sP)
{
#pragma clang fp contract(off)
  const int wid = (int)((blockIdx.x * blockDim.x + threadIdx.x) >> 6);
  const int lane = threadIdx.x & 63;
  if (wid >= NBN * FW * DBINS) return;
  const int bn  = wid / (FW * DBINS);
  const int rem = wid - bn * (FW * DBINS);
  const int col = rem / DBINS;
  const int dm1 = rem - col * DBINS;
  const int b   = bn / NCAM;

  const float* cm = wsf + WS_CMB + bn * 9;
  const float* tr = trans + bn * 3;
  const float dd = 1.0f + (float)dm1;
  const float px = wsf[WS_XS + col] * dd;
  const float py0 = wsf[WS_YS + 0] * dd;
  const float e0 = (cm[0]*px + cm[1]*py0) + cm[2]*dd;
  const float e1 = (cm[3]*px + cm[4]*py0) + cm[5]*dd;
  const float g0 = e0 + tr[0];
  const float g1 = e1 + tr[1];
  const int gx = (int)truncf((g0 + 51.2f) / 0.8f);
  const int gy = (int)truncf((g1 + 51.2f) / 0.8f);
  if (gx < 0 || gx >= NXG || gy < 0 || gy >= NYG) return;

  const int r = lane & 15;
  const float pyr = wsf[WS_YS + r] * dd;
  const float e2 = (cm[6]*px + cm[7]*pyr) + cm[8]*dd;
  const float g2 = e2 + tr[2];
  const int gz = (int)truncf((g2 + 10.0f) / 20.0f);
  unsigned long long mask = __ballot(gz == 0) & 0xFFFFull;
  if (mask == 0) return;

  const float dep_r = dep[(size_t)bn * sBN + (size_t)dm1 * sD + (size_t)(r*FW + col) * sP];
  const float* ctxbase = ctx + ((size_t)bn * NPIX + col) * C_TR + lane;

  float acc = 0.0f;
  #pragma unroll
  for (int row = 0; row < FH; ++row) {
    if ((mask >> row) & 1ull) {    // wave-uniform
      float dv = __shfl(dep_r, row, 64);
      acc += dv * ctxbase[(size_t)(row * FW) * C_TR];
    }
  }
  atomicAdd(&bev[(((size_t)(b*NXG + gx) * NYG + gy) * C_TR) + lane], acc);
}

__global__ __launch_bounds__(256) void transpose_kernel(
    const float* __restrict__ bev, float* __restrict__ out)
{
  __shared__ float tile[NYG][C_TR + 1];
  const int b  = blockIdx.x >> 7;
  const int gx = blockIdx.x & 127;
  const float* src = bev + ((size_t)(b * NXG + gx) * NYG) * C_TR;
  const int t = threadIdx.x;
  #pragma unroll
  for (int i = 0; i < 32; ++i) {
    int idx = t + i * 256;
    tile[idx >> 6][idx & 63] = src[idx];
  }
  __syncthreads();
  const int lane = t & 63;
  const int cw   = t >> 6;
  size_t obase = (size_t)b * (C_TR*NXG*NYG) + (size_t)gx * NYG;
  #pragma unroll
  for (int i = 0; i < 16; ++i) {
    int c = cw + i * 4;
    out[obase + (size_t)c * (NXG*NYG) + lane]      = tile[lane][c];
    out[obase + (size_t)c * (NXG*NYG) + 64 + lane] = tile[64 + lane][c];
  }
}

// ---------- FALLBACK (R8 path, proven): o-major GEMM + in-place softmax ----
__global__ __launch_bounds__(256) void gemm_fb_kernel(
    const float* __restrict__ x, const float* __restrict__ w,
    const float* __restrict__ bias, float* __restrict__ feat,
    float* __restrict__ ctx_t)
{
  __shared__ float Xs[64][32];
  __shared__ float Ws[128][66];
  __shared__ float CtxT[32][C_TR];
  const int bn  = blockIdx.y;
  const int hw0 = blockIdx.x * 32;
  const int t   = threadIdx.x;
  const int tx  = t & 7;
  const int ty  = t >> 3;
  float acc[4][4] = {};
  const float* xb = x + (size_t)bn * C_IN * NPIX;

  for (int k0 = 0; k0 < C_IN; k0 += 64) {
    #pragma unroll
    for (int i = 0; i < 8; ++i) {
      int r = (t >> 5) + i * 8;
      Xs[r][t & 31] = xb[(size_t)(k0 + r) * NPIX + hw0 + (t & 31)];
    }
    #pragma unroll
    for (int i = 0; i < 32; ++i) {
      int o = (t >> 6) + i * 4;
      Ws[o][t & 63] = (o < NO) ? w[(size_t)o * C_IN + k0 + (t & 63)] : 0.0f;
    }
    __syncthreads();
    #pragma unroll 8
    for (int k = 0; k < 64; k += 2) {
      float4 xa = *(const float4*)&Xs[k][tx*4];
      float4 xc = *(const float4*)&Xs[k+1][tx*4];
      #pragma unroll
      for (int i = 0; i < 4; ++i) {
        float2 wv = *(const float2*)&Ws[ty*4+i][k];
        acc[i][0] += wv.x*xa.x; acc[i][1] += wv.x*xa.y;
        acc[i][2] += wv.x*xa.z; acc[i][3] += wv.x*xa.w;
        acc[i][0] += wv.y*xc.x; acc[i][1] += wv.y*xc.y;
        acc[i][2] += wv.y*xc.z; acc[i][3] += wv.y*xc.w;
      }
    }
    __syncthreads();
  }
  #pragma unroll
  for (int i = 0; i < 4; ++i) {
    int o = ty*4 + i;
    float bb = (o < NO) ? bias[o] : 0.0f;
    float4 v = make_float4(acc[i][0]+bb, acc[i][1]+bb, acc[i][2]+bb, acc[i][3]+bb);
    *(float4*)&feat[((size_t)bn * NOP + o) * NPIX + hw0 + tx*4] = v;
    if (o >= DBINS && o < NO) {
      int c = o - DBINS;
      CtxT[tx*4+0][c] = v.x; CtxT[tx*4+1][c] = v.y;
      CtxT[tx*4+2][c] = v.z; CtxT[tx*4+3][c] = v.w;
    }
  }
  __syncthreads();
  const float* src = &CtxT[0][0];
  float* dst = ctx_t + ((size_t)bn * NPIX + hw0) * C_TR;
  #pragma unroll
  for (int k = 0; k < 2; ++k) {
    int f = (t + 256*k) * 4;
    *(float4*)&dst[f] = *(const float4*)&src[f];
  }
}

__global__ __launch_bounds__(256) void softmax_fb_kernel(float* __restrict__ feat)
{
  const int gwid = (int)((blockIdx.x * blockDim.x + threadIdx.x) >> 6);
  const int lane = threadIdx.x & 63;
  if (gwid >= NBN * NPIX) return;
  const int bn = gwid / NPIX;
  const int hw = gwid - bn * NPIX;
  float* fb = feat + (size_t)bn * NOP * NPIX + hw;
  float logit = (lane < DBINS) ? fb[(size_t)lane * NPIX] : -__builtin_inff();
  float m = logit;
  #pragma unroll
  for (int off = 32; off; off >>= 1) m = fmaxf(m, __shfl_xor(m, off, 64));
  float e = (lane < DBINS) ? expf(logit - m) : 0.0f;
  float s = e;
  #pragma unroll
  for (int off = 32; off; off >>= 1) s += __shfl_xor(s, off, 64);
  if (lane < DBINS) fb[(size_t)lane * NPIX] = e / s;
}

extern "C" void kernel_launch(void* const* d_in, const int* in_sizes, int n_in,
                              void* d_out, int out_size, void* d_ws, size_t ws_size,
                              hipStream_t stream)
{
  const float* x       = (const float*)d_in[0];
  const float* rots    = (const float*)d_in[1];
  const float* trans   = (const float*)d_in[2];
  const float* intrins = (const float*)d_in[3];
  const float* wd      = (const float*)d_in[4];
  const float* bd      = (const float*)d_in[5];
  float* out = (float*)d_out;
  float* wsf = (float*)d_ws;

  if (ws_size >= (size_t)WS_FAST_TOTALF * sizeof(float)) {
    float* wT    = wsf + WSP_WT;
    float* part  = wsf + WSP_PART;
    float* depth = wsf + WSP_DEP;
    float* ctx_t = wsf + WSP_CTX;
    float* bev   = wsf + WSP_BEV;
    zero_prep_kernel<<<2048, 256, 0, stream>>>(
        (float4*)bev, BEV_SZ/4, rots, intrins, wd, wT, wsf);
    gemm_split_kernel<<<dim3(NPIX/32, NBN, NCH), 256, 0, stream>>>(x, wT, part);
    combine_kernel<<<(NBN*NPIX)/4, 256, 0, stream>>>(part, bd, depth, ctx_t);
    agg_kernel<<<(NBN*FW*DBINS + 3)/4, 256, 0, stream>>>(
        wsf, trans, depth, ctx_t, bev,
        (size_t)NPIX * C_TR, (size_t)1, (size_t)C_TR);
    transpose_kernel<<<NBATCH*NXG, 256, 0, stream>>>(bev, out);
  } else {
    float* feat  = wsf + WS_FEAT;
    float* ctx_t = wsf + WS_CTX;
    float* bev   = wsf + WS_BEV;
    zero_prep_kernel<<<2048, 256, 0, stream>>>(
        (float4*)bev, BEV_SZ/4, rots, intrins, wd, nullptr, wsf);
    gemm_fb_kernel<<<dim3(NPIX/32, NBN), 256, 0, stream>>>(x, wd, bd, feat, ctx_t);
    softmax_fb_kernel<<<(NBN*NPIX)/4, 256, 0, stream>>>(feat);
    agg_kernel<<<(NBN*FW*DBINS + 3)/4, 256, 0, stream>>>(
        wsf, trans, feat, ctx_t, bev,
        (size_t)NOP * NPIX, (size_t)NPIX, (size_t)1);
    transpose_kernel<<<NBATCH*NXG, 256, 0, stream>>>(bev, out);
  }
}

// Round 16
// 76.653 us; speedup vs baseline: 1.2179x; 1.0446x over previous
//
#include <hip/hip_runtime.h>
#include <cstddef>
#include <cstdint>
#include <math.h>

#define C_IN   512
#define C_TR   64
#define DBINS  59
#define NO     123   // DBINS + C_TR
#define NOP    128   // padded
#define FH     16
#define FW     44
#define NPIX   704
#define NCAM   6
#define NBATCH 2
#define NBN    12
#define NXG    128
#define NYG    128
#define NCH    4     // split-K chunks (8 doubled combine traffic — R15 lesson)
#define KCH    (C_IN/NCH)   // 128

// ---- shared tables (both paths) ----
#define WS_CMB     0
#define WS_XS      128
#define WS_YS      176

// ---- fast path layout (floats) ----
#define WSP_WT     256
#define WT_SZ      (C_IN*NOP)                  // 65,536
#define WSP_PART   (WSP_WT + WT_SZ)
#define PART_SZ    (NCH*NBN*NPIX*NOP)          // 4,325,376
#define WSP_DEP    (WSP_PART + PART_SZ)
#define DEP_SZ     (NBN*NPIX*C_TR)
#define WSP_CTX    (WSP_DEP + DEP_SZ)
#define WSP_BEV    (WSP_CTX + DEP_SZ)
#define BEV_SZ     (NBATCH*NXG*NYG*C_TR)
#define WS_FAST_TOTALF (WSP_BEV + BEV_SZ)      // ~30.3MB (ws=256MB, fits)

// ---- fallback (R8) layout ----
#define WS_FEAT    256
#define WS_CTX     (WS_FEAT + NBN*NOP*NPIX)
#define WS_BEV     (WS_CTX + NBN*NPIX*C_TR)

__device__ void prep_body(const float* __restrict__ rots,
                          const float* __restrict__ intrins,
                          float* __restrict__ wsf, int t)
{
#pragma clang fp contract(off)
  if (t < NBN) {
    // np.linalg.inv f32 == sgetrf + triangular solve with RECIPROCAL-MULTIPLY
    // (LAPACK pre-inverts the diagonal). 1-ulp vs Cramer-division in inv[0][2]
    // — decides voxel-boundary points (R7 evidence). DO NOT TOUCH.
    const float* K = intrins + t * 9;
    const float* R = rots + t * 9;
    float A[3][3] = {{K[0],K[1],K[2]},{K[3],K[4],K[5]},{K[6],K[7],K[8]}};
    int piv[3] = {0,1,2};
    for (int k = 0; k < 2; ++k) {
      int p = k; float mx = fabsf(A[k][k]);
      for (int r = k+1; r < 3; ++r) { float v = fabsf(A[r][k]); if (v > mx) { mx = v; p = r; } }
      if (p != k) {
        for (int j = 0; j < 3; ++j) { float tmp = A[k][j]; A[k][j] = A[p][j]; A[p][j] = tmp; }
        int ti = piv[k]; piv[k] = piv[p]; piv[p] = ti;
      }
      float rk = 1.0f / A[k][k];
      for (int r = k+1; r < 3; ++r) {
        float l = A[r][k] * rk;
        A[r][k] = l;
        for (int j = k+1; j < 3; ++j) A[r][j] = A[r][j] - l * A[k][j];
      }
    }
    float r0 = 1.0f / A[0][0], r1 = 1.0f / A[1][1], r2 = 1.0f / A[2][2];
    float inv[3][3];
    for (int j = 0; j < 3; ++j) {
      float b0 = (piv[0]==j) ? 1.0f : 0.0f;
      float b1 = (piv[1]==j) ? 1.0f : 0.0f;
      float b2 = (piv[2]==j) ? 1.0f : 0.0f;
      float y0 = b0;
      float y1 = b1 - A[1][0]*y0;
      float y2 = (b2 - A[2][0]*y0) - A[2][1]*y1;
      float x2 = y2 * r2;
      float x1 = (y1 - A[1][2]*x2) * r1;
      float x0 = ((y0 - A[0][1]*x1) - A[0][2]*x2) * r0;
      inv[0][j] = x0; inv[1][j] = x1; inv[2][j] = x2;
    }
    float* cm = wsf + WS_CMB + t * 9;
    #pragma unroll
    for (int i = 0; i < 3; ++i)
      #pragma unroll
      for (int j = 0; j < 3; ++j)
        cm[i*3+j] = (R[i*3+0]*inv[0][j] + R[i*3+1]*inv[1][j]) + R[i*3+2]*inv[2][j];
  }
  if (t < FW) wsf[WS_XS + t] = (t == FW-1) ? 703.0f : (float)((double)t * (703.0 / 43.0));
  if (t < FH) wsf[WS_YS + t] = (t == FH-1) ? 255.0f : (float)((double)t * 17.0);
}

// zero bev + transpose W to k-major (wT, L2-resident) + (block 0) tables
__global__ __launch_bounds__(256) void zero_prep_kernel(
    float4* __restrict__ bevp, int n4,
    const float* __restrict__ rots, const float* __restrict__ intrins,
    const float* __restrict__ w, float* __restrict__ wT,
    float* __restrict__ wsf)
{
  int i = blockIdx.x * 256 + threadIdx.x;
  const int stride = gridDim.x * 256;
  for (int j = i; j < n4; j += stride) bevp[j] = make_float4(0.f, 0.f, 0.f, 0.f);
  if (wT) {
    for (int j = i; j < C_IN * NOP; j += stride) {
      int k = j >> 7, o = j & 127;               // coalesced wT write
      wT[j] = (o < NO) ? w[(size_t)o * C_IN + k] : 0.0f;
    }
  }
  if (blockIdx.x == 0 && threadIdx.x < 64)
    prep_body(rots, intrins, wsf, threadIdx.x);
}

// ---------- FAST PATH: split-K GEMM; W from global (L2), X from LDS ----------
__global__ __launch_bounds__(256) void gemm_split_kernel(
    const float* __restrict__ x, const float* __restrict__ wT,
    float* __restrict__ partial)
{
  __shared__ float smem[32 * 128];                 // 16 KB (Xs + PT epilogue)
  float (*Xs)[32] = (float(*)[32])smem;            // [32 k][32 pix]
  const int bn  = blockIdx.y;
  const int ch  = blockIdx.z;
  const int hw0 = blockIdx.x * 32;
  const int t   = threadIdx.x;
  const int tx  = t & 7;     // pixel quad
  const int ty  = t >> 3;    // output quad (0..31)
  float acc[4][4] = {};      // [o_i][pix_j]
  const float* xb = x + (size_t)bn * C_IN * NPIX;
  const int k0c = ch * KCH;

  for (int ks = 0; ks < KCH; ks += 32) {
    const int k0 = k0c + ks;
    #pragma unroll
    for (int i = 0; i < 4; ++i) {
      int k = (t >> 5) + i * 8;
      Xs[k][t & 31] = xb[(size_t)(k0 + k) * NPIX + hw0 + (t & 31)];
    }
    __syncthreads();
    const float4* wp = (const float4*)(wT + (size_t)k0 * NOP) + ty;  // stride 32 float4/row
    #pragma unroll 8
    for (int k = 0; k < 32; ++k) {
      float4 xa = *(const float4*)&Xs[k][tx*4];
      float4 wv = wp[k * 32];                      // global b128, L2-hit
      acc[0][0] += wv.x*xa.x; acc[0][1] += wv.x*xa.y; acc[0][2] += wv.x*xa.z; acc[0][3] += wv.x*xa.w;
      acc[1][0] += wv.y*xa.x; acc[1][1] += wv.y*xa.y; acc[1][2] += wv.y*xa.z; acc[1][3] += wv.y*xa.w;
      acc[2][0] += wv.z*xa.x; acc[2][1] += wv.z*xa.y; acc[2][2] += wv.z*xa.z; acc[2][3] += wv.z*xa.w;
      acc[3][0] += wv.w*xa.x; acc[3][1] += wv.w*xa.y; acc[3][2] += wv.w*xa.z; acc[3][3] += wv.w*xa.w;
    }
    __syncthreads();
  }
  // epilogue: transpose to pixel-major via LDS, coalesced global write
  float (*PT)[128] = (float(*)[128])smem;          // [32 pix][128 o] aligned
  #pragma unroll
  for (int j = 0; j < 4; ++j) {
    float4 v = make_float4(acc[0][j], acc[1][j], acc[2][j], acc[3][j]);
    *(float4*)&PT[tx*4 + j][ty*4] = v;
  }
  __syncthreads();
  float* dst = partial + ((size_t)(ch*NBN + bn) * NPIX + hw0) * NOP;
  #pragma unroll
  for (int p = 0; p < 4; ++p) {
    int pix = (t >> 5) + p * 8;
    int o4  = (t & 31) * 4;
    *(float4*)&dst[(size_t)pix * NOP + o4] = *(const float4*)&PT[pix][o4];
  }
}

// combine partials + bias, in-register softmax, emit depth + ctx (chan-last)
__global__ __launch_bounds__(256) void combine_kernel(
    const float* __restrict__ partial, const float* __restrict__ bias,
    float* __restrict__ depth, float* __restrict__ ctx_t)
{
  const int gid  = (int)((blockIdx.x * blockDim.x + threadIdx.x) >> 6);
  const int lane = threadIdx.x & 63;
  if (gid >= NBN * NPIX) return;
  const int bn  = gid / NPIX;
  const int pix = gid - bn * NPIX;

  float v0 = 0.0f, v1 = 0.0f;
  #pragma unroll
  for (int ch = 0; ch < NCH; ++ch) {
    const float* p = partial + ((size_t)(ch*NBN + bn) * NPIX + pix) * NOP;
    v0 += p[lane];
    v1 += p[lane + 64];
  }
  v0 += bias[lane];
  v1 += (lane + 64 < NO) ? bias[lane + 64] : 0.0f;

  float logit = (lane < DBINS) ? v0 : -__builtin_inff();
  float m = logit;
  #pragma unroll
  for (int off = 32; off; off >>= 1) m = fmaxf(m, __shfl_xor(m, off, 64));
  float e = (lane < DBINS) ? expf(logit - m) : 0.0f;
  float s = e;
  #pragma unroll
  for (int off = 32; off; off >>= 1) s += __shfl_xor(s, off, 64);

  if (lane < DBINS) depth[(size_t)gid * C_TR + lane] = e / s;

  // ctx channel c = lane: value at o = 59 + c.
  // BOTH shuffles unconditional (full exec) — divergent shfl was R9/R10 bug.
  float a  = __shfl(v0, (DBINS + lane) & 63, 64);        // lanes 0..4 use
  float b2 = __shfl(v1, (DBINS + lane - 64) & 63, 64);   // lanes 5..63 use
  float ctxv = (lane < 5) ? a : b2;
  ctx_t[(size_t)gid * C_TR + lane] = ctxv;
}

// One wave per (bn,col,d); 16 rows aggregated in regs -> one 64-lane atomic.
__global__ __launch_bounds__(256) void agg_kernel(
    const float* __restrict__ wsf, const float* __restrict__ trans,
    const float* __restrict__ dep, const float* __restrict__ ctx,
    float* __restrict__ bev, size_t sBN, size_t sD, size_t sP)
{
#pragma clang fp contract(off)
  const int wid = (int)((blockIdx.x * blockDim.x + threadIdx.x) >> 6);
  const int lane = threadIdx.x & 63;
  if (wid >= NBN * FW * DBINS) return;
  const int bn  = wid / (FW * DBINS);
  const int rem = wid - bn * (FW * DBINS);
  const int col = rem / DBINS;
  const int dm1 = rem - col * DBINS;
  const int b   = bn / NCAM;

  const float* cm = wsf + WS_CMB + bn * 9;
  const float* tr = trans + bn * 3;
  const float dd = 1.0f + (float)dm1;
  const float px = wsf[WS_XS + col] * dd;
  const float py0 = wsf[WS_YS + 0] * dd;
  const float e0 = (cm[0]*px + cm[1]*py0) + cm[2]*dd;
  const float e1 = (cm[3]*px + cm[4]*py0) + cm[5]*dd;
  const float g0 = e0 + tr[0];
  const float g1 = e1 + tr[1];
  const int gx = (int)truncf((g0 + 51.2f) / 0.8f);
  const int gy = (int)truncf((g1 + 51.2f) / 0.8f);
  if (gx < 0 || gx >= NXG || gy < 0 || gy >= NYG) return;

  const int r = lane & 15;
  const float pyr = wsf[WS_YS + r] * dd;
  const float e2 = (cm[6]*px + cm[7]*pyr) + cm[8]*dd;
  const float g2 = e2 + tr[2];
  const int gz = (int)truncf((g2 + 10.0f) / 20.0f);
  unsigned long long mask = __ballot(gz == 0) & 0xFFFFull;
  if (mask == 0) return;

  const float dep_r = dep[(size_t)bn * sBN + (size_t)dm1 * sD + (size_t)(r*FW + col) * sP];
  const float* ctxbase = ctx + ((size_t)bn * NPIX + col) * C_TR + lane;

  float acc = 0.0f;
  #pragma unroll
  for (int row = 0; row < FH; ++row) {
    if ((mask >> row) & 1ull) {    // wave-uniform
      float dv = __shfl(dep_r, row, 64);
      acc += dv * ctxbase[(size_t)(row * FW) * C_TR];
    }
  }
  atomicAdd(&bev[(((size_t)(b*NXG + gx) * NYG + gy) * C_TR) + lane], acc);
}

__global__ __launch_bounds__(256) void transpose_kernel(
    const float* __restrict__ bev, float* __restrict__ out)
{
  __shared__ float tile[NYG][C_TR + 1];
  const int b  = blockIdx.x >> 7;
  const int gx = blockIdx.x & 127;
  const float* src = bev + ((size_t)(b * NXG + gx) * NYG) * C_TR;
  const int t = threadIdx.x;
  #pragma unroll
  for (int i = 0; i < 32; ++i) {
    int idx = t + i * 256;
    tile[idx >> 6][idx & 63] = src[idx];
  }
  __syncthreads();
  const int lane = t & 63;
  const int cw   = t >> 6;
  size_t obase = (size_t)b * (C_TR*NXG*NYG) + (size_t)gx * NYG;
  #pragma unroll
  for (int i = 0; i < 16; ++i) {
    int c = cw + i * 4;
    out[obase + (size_t)c * (NXG*NYG) + lane]      = tile[lane][c];
    out[obase + (size_t)c * (NXG*NYG) + 64 + lane] = tile[64 + lane][c];
  }
}

// ---------- FALLBACK (R8 path, proven): o-major GEMM + in-place softmax ----
__global__ __launch_bounds__(256) void gemm_fb_kernel(
    const float* __restrict__ x, const float* __restrict__ w,
    const float* __restrict__ bias, float* __restrict__ feat,
    float* __restrict__ ctx_t)
{
  __shared__ float Xs[64][32];
  __shared__ float Ws[128][66];
  __shared__ float CtxT[32][C_TR];
  const int bn  = blockIdx.y;
  const int hw0 = blockIdx.x * 32;
  const int t   = threadIdx.x;
  const int tx  = t & 7;
  const int ty  = t >> 3;
  float acc[4][4] = {};
  const float* xb = x + (size_t)bn * C_IN * NPIX;

  for (int k0 = 0; k0 < C_IN; k0 += 64) {
    #pragma unroll
    for (int i = 0; i < 8; ++i) {
      int r = (t >> 5) + i * 8;
      Xs[r][t & 31] = xb[(size_t)(k0 + r) * NPIX + hw0 + (t & 31)];
    }
    #pragma unroll
    for (int i = 0; i < 32; ++i) {
      int o = (t >> 6) + i * 4;
      Ws[o][t & 63] = (o < NO) ? w[(size_t)o * C_IN + k0 + (t & 63)] : 0.0f;
    }
    __syncthreads();
    #pragma unroll 8
    for (int k = 0; k < 64; k += 2) {
      float4 xa = *(const float4*)&Xs[k][tx*4];
      float4 xc = *(const float4*)&Xs[k+1][tx*4];
      #pragma unroll
      for (int i = 0; i < 4; ++i) {
        float2 wv = *(const float2*)&Ws[ty*4+i][k];
        acc[i][0] += wv.x*xa.x; acc[i][1] += wv.x*xa.y;
        acc[i][2] += wv.x*xa.z; acc[i][3] += wv.x*xa.w;
        acc[i][0] += wv.y*xc.x; acc[i][1] += wv.y*xc.y;
        acc[i][2] += wv.y*xc.z; acc[i][3] += wv.y*xc.w;
      }
    }
    __syncthreads();
  }
  #pragma unroll
  for (int i = 0; i < 4; ++i) {
    int o = ty*4 + i;
    float bb = (o < NO) ? bias[o] : 0.0f;
    float4 v = make_float4(acc[i][0]+bb, acc[i][1]+bb, acc[i][2]+bb, acc[i][3]+bb);
    *(float4*)&feat[((size_t)bn * NOP + o) * NPIX + hw0 + tx*4] = v;
    if (o >= DBINS && o < NO) {
      int c = o - DBINS;
      CtxT[tx*4+0][c] = v.x; CtxT[tx*4+1][c] = v.y;
      CtxT[tx*4+2][c] = v.z; CtxT[tx*4+3][c] = v.w;
    }
  }
  __syncthreads();
  const float* src = &CtxT[0][0];
  float* dst = ctx_t + ((size_t)bn * NPIX + hw0) * C_TR;
  #pragma unroll
  for (int k = 0; k < 2; ++k) {
    int f = (t + 256*k) * 4;
    *(float4*)&dst[f] = *(const float4*)&src[f];
  }
}

__global__ __launch_bounds__(256) void softmax_fb_kernel(float* __restrict__ feat)
{
  const int gwid = (int)((blockIdx.x * blockDim.x + threadIdx.x) >> 6);
  const int lane = threadIdx.x & 63;
  if (gwid >= NBN * NPIX) return;
  const int bn = gwid / NPIX;
  const int hw = gwid - bn * NPIX;
  float* fb = feat + (size_t)bn * NOP * NPIX + hw;
  float logit = (lane < DBINS) ? fb[(size_t)lane * NPIX] : -__builtin_inff();
  float m = logit;
  #pragma unroll
  for (int off = 32; off; off >>= 1) m = fmaxf(m, __shfl_xor(m, off, 64));
  float e = (lane < DBINS) ? expf(logit - m) : 0.0f;
  float s = e;
  #pragma unroll
  for (int off = 32; off; off >>= 1) s += __shfl_xor(s, off, 64);
  if (lane < DBINS) fb[(size_t)lane * NPIX] = e / s;
}

extern "C" void kernel_launch(void* const* d_in, const int* in_sizes, int n_in,
                              void* d_out, int out_size, void* d_ws, size_t ws_size,
                              hipStream_t stream)
{
  const float* x       = (const float*)d_in[0];
  const float* rots    = (const float*)d_in[1];
  const float* trans   = (const float*)d_in[2];
  const float* intrins = (const float*)d_in[3];
  const float* wd      = (const float*)d_in[4];
  const float* bd      = (const float*)d_in[5];
  float* out = (float*)d_out;
  float* wsf = (float*)d_ws;

  if (ws_size >= (size_t)WS_FAST_TOTALF * sizeof(float)) {
    float* wT    = wsf + WSP_WT;
    float* part  = wsf + WSP_PART;
    float* depth = wsf + WSP_DEP;
    float* ctx_t = wsf + WSP_CTX;
    float* bev   = wsf + WSP_BEV;
    zero_prep_kernel<<<2048, 256, 0, stream>>>(
        (float4*)bev, BEV_SZ/4, rots, intrins, wd, wT, wsf);
    gemm_split_kernel<<<dim3(NPIX/32, NBN, NCH), 256, 0, stream>>>(x, wT, part);
    combine_kernel<<<(NBN*NPIX)/4, 256, 0, stream>>>(part, bd, depth, ctx_t);
    agg_kernel<<<(NBN*FW*DBINS + 3)/4, 256, 0, stream>>>(
        wsf, trans, depth, ctx_t, bev,
        (size_t)NPIX * C_TR, (size_t)1, (size_t)C_TR);
    transpose_kernel<<<NBATCH*NXG, 256, 0, stream>>>(bev, out);
  } else {
    float* feat  = wsf + WS_FEAT;
    float* ctx_t = wsf + WS_CTX;
    float* bev   = wsf + WS_BEV;
    zero_prep_kernel<<<2048, 256, 0, stream>>>(
        (float4*)bev, BEV_SZ/4, rots, intrins, wd, nullptr, wsf);
    gemm_fb_kernel<<<dim3(NPIX/32, NBN), 256, 0, stream>>>(x, wd, bd, feat, ctx_t);
    softmax_fb_kernel<<<(NBN*NPIX)/4, 256, 0, stream>>>(feat);
    agg_kernel<<<(NBN*FW*DBINS + 3)/4, 256, 0, stream>>>(
        wsf, trans, feat, ctx_t, bev,
        (size_t)NOP * NPIX, (size_t)NPIX, (size_t)1);
    transpose_kernel<<<NBATCH*NXG, 256, 0, stream>>>(bev, out);
  }
}

// Round 17
// 74.216 us; speedup vs baseline: 1.2579x; 1.0328x over previous
//
#include <hip/hip_runtime.h>
#include <cstddef>
#include <cstdint>
#include <math.h>

#define C_IN   512
#define C_TR   64
#define DBINS  59
#define NO     123   // DBINS + C_TR
#define NOP    128   // padded
#define FH     16
#define FW     44
#define NPIX   704
#define NCAM   6
#define NBATCH 2
#define NBN    12
#define NXG    128
#define NYG    128
#define NCH    4     // split-K chunks
#define KCH    (C_IN/NCH)   // 128

// ---- shared tables (both paths) ----
#define WS_CMB     0
#define WS_XS      128
#define WS_YS      176

// ---- fast path layout (floats) ----
#define WSP_WT     256
#define WT_SZ      (C_IN*NOP)
#define WSP_PART   (WSP_WT + WT_SZ)
#define PART_SZ    (NCH*NBN*NPIX*NOP)
#define WSP_BEV    (WSP_PART + PART_SZ)
#define BEV_SZ     (NBATCH*NXG*NYG*C_TR)
#define WS_FAST_TOTALF (WSP_BEV + BEV_SZ)      // ~26MB (ws=256MB, fits)

// ---- fallback (R8) layout ----
#define WS_FEAT    256
#define WS_CTX     (WS_FEAT + NBN*NOP*NPIX)
#define WS_BEV     (WS_CTX + NBN*NPIX*C_TR)

__device__ void prep_body(const float* __restrict__ rots,
                          const float* __restrict__ intrins,
                          float* __restrict__ wsf, int t)
{
#pragma clang fp contract(off)
  if (t < NBN) {
    // np.linalg.inv f32 == sgetrf + triangular solve with RECIPROCAL-MULTIPLY
    // (LAPACK pre-inverts the diagonal). 1-ulp vs Cramer-division in inv[0][2]
    // — decides voxel-boundary points (R7 evidence). DO NOT TOUCH.
    const float* K = intrins + t * 9;
    const float* R = rots + t * 9;
    float A[3][3] = {{K[0],K[1],K[2]},{K[3],K[4],K[5]},{K[6],K[7],K[8]}};
    int piv[3] = {0,1,2};
    for (int k = 0; k < 2; ++k) {
      int p = k; float mx = fabsf(A[k][k]);
      for (int r = k+1; r < 3; ++r) { float v = fabsf(A[r][k]); if (v > mx) { mx = v; p = r; } }
      if (p != k) {
        for (int j = 0; j < 3; ++j) { float tmp = A[k][j]; A[k][j] = A[p][j]; A[p][j] = tmp; }
        int ti = piv[k]; piv[k] = piv[p]; piv[p] = ti;
      }
      float rk = 1.0f / A[k][k];
      for (int r = k+1; r < 3; ++r) {
        float l = A[r][k] * rk;
        A[r][k] = l;
        for (int j = k+1; j < 3; ++j) A[r][j] = A[r][j] - l * A[k][j];
      }
    }
    float r0 = 1.0f / A[0][0], r1 = 1.0f / A[1][1], r2 = 1.0f / A[2][2];
    float inv[3][3];
    for (int j = 0; j < 3; ++j) {
      float b0 = (piv[0]==j) ? 1.0f : 0.0f;
      float b1 = (piv[1]==j) ? 1.0f : 0.0f;
      float b2 = (piv[2]==j) ? 1.0f : 0.0f;
      float y0 = b0;
      float y1 = b1 - A[1][0]*y0;
      float y2 = (b2 - A[2][0]*y0) - A[2][1]*y1;
      float x2 = y2 * r2;
      float x1 = (y1 - A[1][2]*x2) * r1;
      float x0 = ((y0 - A[0][1]*x1) - A[0][2]*x2) * r0;
      inv[0][j] = x0; inv[1][j] = x1; inv[2][j] = x2;
    }
    float* cm = wsf + WS_CMB + t * 9;
    #pragma unroll
    for (int i = 0; i < 3; ++i)
      #pragma unroll
      for (int j = 0; j < 3; ++j)
        cm[i*3+j] = (R[i*3+0]*inv[0][j] + R[i*3+1]*inv[1][j]) + R[i*3+2]*inv[2][j];
  }
  if (t < FW) wsf[WS_XS + t] = (t == FW-1) ? 703.0f : (float)((double)t * (703.0 / 43.0));
  if (t < FH) wsf[WS_YS + t] = (t == FH-1) ? 255.0f : (float)((double)t * 17.0);
}

// zero bev + transpose W to k-major (wT, L2-resident) + (block 0) tables
__global__ __launch_bounds__(256) void zero_prep_kernel(
    float4* __restrict__ bevp, int n4,
    const float* __restrict__ rots, const float* __restrict__ intrins,
    const float* __restrict__ w, float* __restrict__ wT,
    float* __restrict__ wsf)
{
  int i = blockIdx.x * 256 + threadIdx.x;
  const int stride = gridDim.x * 256;
  for (int j = i; j < n4; j += stride) bevp[j] = make_float4(0.f, 0.f, 0.f, 0.f);
  if (wT) {
    for (int j = i; j < C_IN * NOP; j += stride) {
      int k = j >> 7, o = j & 127;
      wT[j] = (o < NO) ? w[(size_t)o * C_IN + k] : 0.0f;
    }
  }
  if (blockIdx.x == 0 && threadIdx.x < 64)
    prep_body(rots, intrins, wsf, threadIdx.x);
}

// ---------- FAST PATH: split-K GEMM; W from global (L2), X from LDS ----------
__global__ __launch_bounds__(256) void gemm_split_kernel(
    const float* __restrict__ x, const float* __restrict__ wT,
    float* __restrict__ partial)
{
  __shared__ float smem[32 * 128];                 // 16 KB (Xs + PT epilogue)
  float (*Xs)[32] = (float(*)[32])smem;            // [32 k][32 pix]
  const int bn  = blockIdx.y;
  const int ch  = blockIdx.z;
  const int hw0 = blockIdx.x * 32;
  const int t   = threadIdx.x;
  const int tx  = t & 7;     // pixel quad
  const int ty  = t >> 3;    // output quad (0..31)
  float acc[4][4] = {};      // [o_i][pix_j]
  const float* xb = x + (size_t)bn * C_IN * NPIX;
  const int k0c = ch * KCH;

  for (int ks = 0; ks < KCH; ks += 32) {
    const int k0 = k0c + ks;
    #pragma unroll
    for (int i = 0; i < 4; ++i) {
      int k = (t >> 5) + i * 8;
      Xs[k][t & 31] = xb[(size_t)(k0 + k) * NPIX + hw0 + (t & 31)];
    }
    __syncthreads();
    const float4* wp = (const float4*)(wT + (size_t)k0 * NOP) + ty;
    #pragma unroll 8
    for (int k = 0; k < 32; ++k) {
      float4 xa = *(const float4*)&Xs[k][tx*4];
      float4 wv = wp[k * 32];                      // global b128, L2-hit
      acc[0][0] += wv.x*xa.x; acc[0][1] += wv.x*xa.y; acc[0][2] += wv.x*xa.z; acc[0][3] += wv.x*xa.w;
      acc[1][0] += wv.y*xa.x; acc[1][1] += wv.y*xa.y; acc[1][2] += wv.y*xa.z; acc[1][3] += wv.y*xa.w;
      acc[2][0] += wv.z*xa.x; acc[2][1] += wv.z*xa.y; acc[2][2] += wv.z*xa.z; acc[2][3] += wv.z*xa.w;
      acc[3][0] += wv.w*xa.x; acc[3][1] += wv.w*xa.y; acc[3][2] += wv.w*xa.z; acc[3][3] += wv.w*xa.w;
    }
    __syncthreads();
  }
  float (*PT)[128] = (float(*)[128])smem;          // [32 pix][128 o] aligned
  #pragma unroll
  for (int j = 0; j < 4; ++j) {
    float4 v = make_float4(acc[0][j], acc[1][j], acc[2][j], acc[3][j]);
    *(float4*)&PT[tx*4 + j][ty*4] = v;
  }
  __syncthreads();
  float* dst = partial + ((size_t)(ch*NBN + bn) * NPIX + hw0) * NOP;
  #pragma unroll
  for (int p = 0; p < 4; ++p) {
    int pix = (t >> 5) + p * 8;
    int o4  = (t & 31) * 4;
    *(float4*)&dst[(size_t)pix * NOP + o4] = *(const float4*)&PT[pix][o4];
  }
}

// ---------- FUSED combine+agg: one block per (bn, col) ----------
// Phase 1: 4 waves x 4 rows — per-pixel softmax (bit-identical to combine),
// depth/ctx parked in LDS. Phase 2: waves round-robin the 59 depth bins —
// identical contract-off geometry, ballot over 16 rows, one 64-lane atomic.
__global__ __launch_bounds__(256) void sm_agg_kernel(
    const float* __restrict__ wsf, const float* __restrict__ trans,
    const float* __restrict__ partial, const float* __restrict__ bias,
    float* __restrict__ bev)
{
#pragma clang fp contract(off)
  __shared__ float dep_s[FH][60];   // stride 60: 2-way bank alias (free)
  __shared__ float ctx_s[FH][C_TR];
  const int blk  = blockIdx.x;
  const int bn   = blk / FW;
  const int col  = blk - bn * FW;
  const int wave = threadIdx.x >> 6;
  const int lane = threadIdx.x & 63;
  const int b    = bn / NCAM;

  // ---- phase 1: softmax for rows 4*wave .. 4*wave+3 ----
  #pragma unroll
  for (int rr = 0; rr < 4; ++rr) {
    const int row = wave * 4 + rr;
    const int pix = row * FW + col;
    float v0 = 0.0f, v1 = 0.0f;
    #pragma unroll
    for (int ch = 0; ch < NCH; ++ch) {
      const float* p = partial + ((size_t)(ch*NBN + bn) * NPIX + pix) * NOP;
      v0 += p[lane];
      v1 += p[lane + 64];
    }
    v0 += bias[lane];
    v1 += (lane + 64 < NO) ? bias[lane + 64] : 0.0f;

    float logit = (lane < DBINS) ? v0 : -__builtin_inff();
    float m = logit;
    #pragma unroll
    for (int off = 32; off; off >>= 1) m = fmaxf(m, __shfl_xor(m, off, 64));
    float e = (lane < DBINS) ? expf(logit - m) : 0.0f;
    float s = e;
    #pragma unroll
    for (int off = 32; off; off >>= 1) s += __shfl_xor(s, off, 64);
    if (lane < DBINS) dep_s[row][lane] = e / s;

    // ctx channel c = lane (o = 59 + c); unconditional shuffles, full exec
    float a  = __shfl(v0, (DBINS + lane) & 63, 64);
    float b2 = __shfl(v1, (DBINS + lane - 64) & 63, 64);
    ctx_s[row][lane] = (lane < 5) ? a : b2;
  }
  __syncthreads();

  // ---- phase 2: depth bins round-robin over waves ----
  const float* cm = wsf + WS_CMB + bn * 9;
  const float* tr = trans + bn * 3;
  const int r = lane & 15;
  for (int dm1 = wave; dm1 < DBINS; dm1 += 4) {
    const float dd = 1.0f + (float)dm1;
    const float px = wsf[WS_XS + col] * dd;
    const float py0 = wsf[WS_YS + 0] * dd;
    const float e0 = (cm[0]*px + cm[1]*py0) + cm[2]*dd;
    const float e1 = (cm[3]*px + cm[4]*py0) + cm[5]*dd;
    const float g0 = e0 + tr[0];
    const float g1 = e1 + tr[1];
    const int gx = (int)truncf((g0 + 51.2f) / 0.8f);
    const int gy = (int)truncf((g1 + 51.2f) / 0.8f);
    if (gx < 0 || gx >= NXG || gy < 0 || gy >= NYG) continue;  // wave-uniform

    const float pyr = wsf[WS_YS + r] * dd;
    const float e2 = (cm[6]*px + cm[7]*pyr) + cm[8]*dd;
    const float g2 = e2 + tr[2];
    const int gz = (int)truncf((g2 + 10.0f) / 20.0f);
    unsigned long long mask = __ballot(gz == 0) & 0xFFFFull;
    if (mask == 0) continue;                                   // wave-uniform

    const float dep_r = dep_s[r][dm1];
    float acc = 0.0f;
    #pragma unroll
    for (int row = 0; row < FH; ++row) {
      if ((mask >> row) & 1ull) {   // wave-uniform
        float dv = __shfl(dep_r, row, 64);
        acc += dv * ctx_s[row][lane];
      }
    }
    atomicAdd(&bev[(((size_t)(b*NXG + gx) * NYG + gy) * C_TR) + lane], acc);
  }
}

__global__ __launch_bounds__(256) void transpose_kernel(
    const float* __restrict__ bev, float* __restrict__ out)
{
  __shared__ float tile[NYG][C_TR + 1];
  const int b  = blockIdx.x >> 7;
  const int gx = blockIdx.x & 127;
  const float* src = bev + ((size_t)(b * NXG + gx) * NYG) * C_TR;
  const int t = threadIdx.x;
  #pragma unroll
  for (int i = 0; i < 32; ++i) {
    int idx = t + i * 256;
    tile[idx >> 6][idx & 63] = src[idx];
  }
  __syncthreads();
  const int lane = t & 63;
  const int cw   = t >> 6;
  size_t obase = (size_t)b * (C_TR*NXG*NYG) + (size_t)gx * NYG;
  #pragma unroll
  for (int i = 0; i < 16; ++i) {
    int c = cw + i * 4;
    out[obase + (size_t)c * (NXG*NYG) + lane]      = tile[lane][c];
    out[obase + (size_t)c * (NXG*NYG) + 64 + lane] = tile[64 + lane][c];
  }
}

// ---------- FALLBACK (R8 path, proven) ----------
__global__ __launch_bounds__(256) void gemm_fb_kernel(
    const float* __restrict__ x, const float* __restrict__ w,
    const float* __restrict__ bias, float* __restrict__ feat,
    float* __restrict__ ctx_t)
{
  __shared__ float Xs[64][32];
  __shared__ float Ws[128][66];
  __shared__ float CtxT[32][C_TR];
  const int bn  = blockIdx.y;
  const int hw0 = blockIdx.x * 32;
  const int t   = threadIdx.x;
  const int tx  = t & 7;
  const int ty  = t >> 3;
  float acc[4][4] = {};
  const float* xb = x + (size_t)bn * C_IN * NPIX;

  for (int k0 = 0; k0 < C_IN; k0 += 64) {
    #pragma unroll
    for (int i = 0; i < 8; ++i) {
      int r = (t >> 5) + i * 8;
      Xs[r][t & 31] = xb[(size_t)(k0 + r) * NPIX + hw0 + (t & 31)];
    }
    #pragma unroll
    for (int i = 0; i < 32; ++i) {
      int o = (t >> 6) + i * 4;
      Ws[o][t & 63] = (o < NO) ? w[(size_t)o * C_IN + k0 + (t & 63)] : 0.0f;
    }
    __syncthreads();
    #pragma unroll 8
    for (int k = 0; k < 64; k += 2) {
      float4 xa = *(const float4*)&Xs[k][tx*4];
      float4 xc = *(const float4*)&Xs[k+1][tx*4];
      #pragma unroll
      for (int i = 0; i < 4; ++i) {
        float2 wv = *(const float2*)&Ws[ty*4+i][k];
        acc[i][0] += wv.x*xa.x; acc[i][1] += wv.x*xa.y;
        acc[i][2] += wv.x*xa.z; acc[i][3] += wv.x*xa.w;
        acc[i][0] += wv.y*xc.x; acc[i][1] += wv.y*xc.y;
        acc[i][2] += wv.y*xc.z; acc[i][3] += wv.y*xc.w;
      }
    }
    __syncthreads();
  }
  #pragma unroll
  for (int i = 0; i < 4; ++i) {
    int o = ty*4 + i;
    float bb = (o < NO) ? bias[o] : 0.0f;
    float4 v = make_float4(acc[i][0]+bb, acc[i][1]+bb, acc[i][2]+bb, acc[i][3]+bb);
    *(float4*)&feat[((size_t)bn * NOP + o) * NPIX + hw0 + tx*4] = v;
    if (o >= DBINS && o < NO) {
      int c = o - DBINS;
      CtxT[tx*4+0][c] = v.x; CtxT[tx*4+1][c] = v.y;
      CtxT[tx*4+2][c] = v.z; CtxT[tx*4+3][c] = v.w;
    }
  }
  __syncthreads();
  const float* src = &CtxT[0][0];
  float* dst = ctx_t + ((size_t)bn * NPIX + hw0) * C_TR;
  #pragma unroll
  for (int k = 0; k < 2; ++k) {
    int f = (t + 256*k) * 4;
    *(float4*)&dst[f] = *(const float4*)&src[f];
  }
}

__global__ __launch_bounds__(256) void softmax_fb_kernel(float* __restrict__ feat)
{
  const int gwid = (int)((blockIdx.x * blockDim.x + threadIdx.x) >> 6);
  const int lane = threadIdx.x & 63;
  if (gwid >= NBN * NPIX) return;
  const int bn = gwid / NPIX;
  const int hw = gwid - bn * NPIX;
  float* fb = feat + (size_t)bn * NOP * NPIX + hw;
  float logit = (lane < DBINS) ? fb[(size_t)lane * NPIX] : -__builtin_inff();
  float m = logit;
  #pragma unroll
  for (int off = 32; off; off >>= 1) m = fmaxf(m, __shfl_xor(m, off, 64));
  float e = (lane < DBINS) ? expf(logit - m) : 0.0f;
  float s = e;
  #pragma unroll
  for (int off = 32; off; off >>= 1) s += __shfl_xor(s, off, 64);
  if (lane < DBINS) fb[(size_t)lane * NPIX] = e / s;
}

// fallback agg (strided dep/ctx addressing)
__global__ __launch_bounds__(256) void agg_kernel(
    const float* __restrict__ wsf, const float* __restrict__ trans,
    const float* __restrict__ dep, const float* __restrict__ ctx,
    float* __restrict__ bev, size_t sBN, size_t sD, size_t sP)
{
#pragma clang fp contract(off)
  const int wid = (int)((blockIdx.x * blockDim.x + threadIdx.x) >> 6);
  const int lane = threadIdx.x & 63;
  if (wid >= NBN * FW * DBINS) return;
  const int bn  = wid / (FW * DBINS);
  const int rem = wid - bn * (FW * DBINS);
  const int col = rem / DBINS;
  const int dm1 = rem - col * DBINS;
  const int b   = bn / NCAM;

  const float* cm = wsf + WS_CMB + bn * 9;
  const float* tr = trans + bn * 3;
  const float dd = 1.0f + (float)dm1;
  const float px = wsf[WS_XS + col] * dd;
  const float py0 = wsf[WS_YS + 0] * dd;
  const float e0 = (cm[0]*px + cm[1]*py0) + cm[2]*dd;
  const float e1 = (cm[3]*px + cm[4]*py0) + cm[5]*dd;
  const float g0 = e0 + tr[0];
  const float g1 = e1 + tr[1];
  const int gx = (int)truncf((g0 + 51.2f) / 0.8f);
  const int gy = (int)truncf((g1 + 51.2f) / 0.8f);
  if (gx < 0 || gx >= NXG || gy < 0 || gy >= NYG) return;

  const int r = lane & 15;
  const float pyr = wsf[WS_YS + r] * dd;
  const float e2 = (cm[6]*px + cm[7]*pyr) + cm[8]*dd;
  const float g2 = e2 + tr[2];
  const int gz = (int)truncf((g2 + 10.0f) / 20.0f);
  unsigned long long mask = __ballot(gz == 0) & 0xFFFFull;
  if (mask == 0) return;

  const float dep_r = dep[(size_t)bn * sBN + (size_t)dm1 * sD + (size_t)(r*FW + col) * sP];
  const float* ctxbase = ctx + ((size_t)bn * NPIX + col) * C_TR + lane;

  float acc = 0.0f;
  #pragma unroll
  for (int row = 0; row < FH; ++row) {
    if ((mask >> row) & 1ull) {
      float dv = __shfl(dep_r, row, 64);
      acc += dv * ctxbase[(size_t)(row * FW) * C_TR];
    }
  }
  atomicAdd(&bev[(((size_t)(b*NXG + gx) * NYG + gy) * C_TR) + lane], acc);
}

extern "C" void kernel_launch(void* const* d_in, const int* in_sizes, int n_in,
                              void* d_out, int out_size, void* d_ws, size_t ws_size,
                              hipStream_t stream)
{
  const float* x       = (const float*)d_in[0];
  const float* rots    = (const float*)d_in[1];
  const float* trans   = (const float*)d_in[2];
  const float* intrins = (const float*)d_in[3];
  const float* wd      = (const float*)d_in[4];
  const float* bd      = (const float*)d_in[5];
  float* out = (float*)d_out;
  float* wsf = (float*)d_ws;

  if (ws_size >= (size_t)WS_FAST_TOTALF * sizeof(float)) {
    float* wT    = wsf + WSP_WT;
    float* part  = wsf + WSP_PART;
    float* bev   = wsf + WSP_BEV;
    zero_prep_kernel<<<2048, 256, 0, stream>>>(
        (float4*)bev, BEV_SZ/4, rots, intrins, wd, wT, wsf);
    gemm_split_kernel<<<dim3(NPIX/32, NBN, NCH), 256, 0, stream>>>(x, wT, part);
    sm_agg_kernel<<<NBN*FW, 256, 0, stream>>>(wsf, trans, part, bd, bev);
    transpose_kernel<<<NBATCH*NXG, 256, 0, stream>>>(bev, out);
  } else {
    float* feat  = wsf + WS_FEAT;
    float* ctx_t = wsf + WS_CTX;
    float* bev   = wsf + WS_BEV;
    zero_prep_kernel<<<2048, 256, 0, stream>>>(
        (float4*)bev, BEV_SZ/4, rots, intrins, wd, nullptr, wsf);
    gemm_fb_kernel<<<dim3(NPIX/32, NBN), 256, 0, stream>>>(x, wd, bd, feat, ctx_t);
    softmax_fb_kernel<<<(NBN*NPIX)/4, 256, 0, stream>>>(feat);
    agg_kernel<<<(NBN*FW*DBINS + 3)/4, 256, 0, stream>>>(
        wsf, trans, feat, ctx_t, bev,
        (size_t)NOP * NPIX, (size_t)NPIX, (size_t)1);
    transpose_kernel<<<NBATCH*NXG, 256, 0, stream>>>(bev, out);
  }
}

// Round 18
// 73.273 us; speedup vs baseline: 1.2741x; 1.0129x over previous
//
#include <hip/hip_runtime.h>
#include <cstddef>
#include <cstdint>
#include <math.h>

#define C_IN   512
#define C_TR   64
#define DBINS  59
#define NO     123   // DBINS + C_TR
#define NOP    128   // padded
#define FH     16
#define FW     44
#define NPIX   704
#define NCAM   6
#define NBATCH 2
#define NBN    12
#define NXG    128
#define NYG    128
#define NCH    4     // split-K chunks
#define KCH    (C_IN/NCH)   // 128

// ---- shared tables (both paths) ----
#define WS_CMB     0
#define WS_XS      128
#define WS_YS      176

// ---- fast path layout (floats) ----
#define WSP_WT     256
#define WT_SZ      (C_IN*NOP)
#define WSP_PART   (WSP_WT + WT_SZ)
#define PART_SZ    (NCH*NBN*NPIX*NOP)
#define WSP_BEV    (WSP_PART + PART_SZ)
#define BEV_SZ     (NBATCH*NXG*NYG*C_TR)
#define WS_FAST_TOTALF (WSP_BEV + BEV_SZ)      // ~26MB (ws=256MB, fits)

// ---- fallback (R8) layout ----
#define WS_FEAT    256
#define WS_CTX     (WS_FEAT + NBN*NOP*NPIX)
#define WS_BEV     (WS_CTX + NBN*NPIX*C_TR)

__device__ void prep_body(const float* __restrict__ rots,
                          const float* __restrict__ intrins,
                          float* __restrict__ wsf, int t)
{
#pragma clang fp contract(off)
  if (t < NBN) {
    // np.linalg.inv f32 == sgetrf + triangular solve with RECIPROCAL-MULTIPLY
    // (LAPACK pre-inverts the diagonal). 1-ulp vs Cramer-division in inv[0][2]
    // — decides voxel-boundary points (R7 evidence). DO NOT TOUCH.
    const float* K = intrins + t * 9;
    const float* R = rots + t * 9;
    float A[3][3] = {{K[0],K[1],K[2]},{K[3],K[4],K[5]},{K[6],K[7],K[8]}};
    int piv[3] = {0,1,2};
    for (int k = 0; k < 2; ++k) {
      int p = k; float mx = fabsf(A[k][k]);
      for (int r = k+1; r < 3; ++r) { float v = fabsf(A[r][k]); if (v > mx) { mx = v; p = r; } }
      if (p != k) {
        for (int j = 0; j < 3; ++j) { float tmp = A[k][j]; A[k][j] = A[p][j]; A[p][j] = tmp; }
        int ti = piv[k]; piv[k] = piv[p]; piv[p] = ti;
      }
      float rk = 1.0f / A[k][k];
      for (int r = k+1; r < 3; ++r) {
        float l = A[r][k] * rk;
        A[r][k] = l;
        for (int j = k+1; j < 3; ++j) A[r][j] = A[r][j] - l * A[k][j];
      }
    }
    float r0 = 1.0f / A[0][0], r1 = 1.0f / A[1][1], r2 = 1.0f / A[2][2];
    float inv[3][3];
    for (int j = 0; j < 3; ++j) {
      float b0 = (piv[0]==j) ? 1.0f : 0.0f;
      float b1 = (piv[1]==j) ? 1.0f : 0.0f;
      float b2 = (piv[2]==j) ? 1.0f : 0.0f;
      float y0 = b0;
      float y1 = b1 - A[1][0]*y0;
      float y2 = (b2 - A[2][0]*y0) - A[2][1]*y1;
      float x2 = y2 * r2;
      float x1 = (y1 - A[1][2]*x2) * r1;
      float x0 = ((y0 - A[0][1]*x1) - A[0][2]*x2) * r0;
      inv[0][j] = x0; inv[1][j] = x1; inv[2][j] = x2;
    }
    float* cm = wsf + WS_CMB + t * 9;
    #pragma unroll
    for (int i = 0; i < 3; ++i)
      #pragma unroll
      for (int j = 0; j < 3; ++j)
        cm[i*3+j] = (R[i*3+0]*inv[0][j] + R[i*3+1]*inv[1][j]) + R[i*3+2]*inv[2][j];
  }
  if (t < FW) wsf[WS_XS + t] = (t == FW-1) ? 703.0f : (float)((double)t * (703.0 / 43.0));
  if (t < FH) wsf[WS_YS + t] = (t == FH-1) ? 255.0f : (float)((double)t * 17.0);
}

// zero bev + transpose W to k-major (wT, L2-resident) + (block 0) tables
__global__ __launch_bounds__(256) void zero_prep_kernel(
    float4* __restrict__ bevp, int n4,
    const float* __restrict__ rots, const float* __restrict__ intrins,
    const float* __restrict__ w, float* __restrict__ wT,
    float* __restrict__ wsf)
{
  int i = blockIdx.x * 256 + threadIdx.x;
  const int stride = gridDim.x * 256;
  for (int j = i; j < n4; j += stride) bevp[j] = make_float4(0.f, 0.f, 0.f, 0.f);
  if (wT) {
    for (int j = i; j < C_IN * NOP; j += stride) {
      int k = j >> 7, o = j & 127;
      wT[j] = (o < NO) ? w[(size_t)o * C_IN + k] : 0.0f;
    }
  }
  if (blockIdx.x == 0 && threadIdx.x < 64)
    prep_body(rots, intrins, wsf, threadIdx.x);
}

// ---------- FAST PATH split-K GEMM ----------
// X: all 128 k staged once in LDS (one barrier; no mid-loop vmcnt drains).
// W: L2-resident k-major wT, manually double-buffered in registers
// (named wa/wb, compile-time indices — avoids scratch) so each 8-k group's
// loads issue a full group ahead of their FMAs.
__global__ __launch_bounds__(256) void gemm_split_kernel(
    const float* __restrict__ x, const float* __restrict__ wT,
    float* __restrict__ partial)
{
  __shared__ float smem[KCH * 32];                 // 16 KB: Xs[128][32] / PT
  float (*Xs)[32] = (float(*)[32])smem;
  const int bn  = blockIdx.y;
  const int ch  = blockIdx.z;
  const int hw0 = blockIdx.x * 32;
  const int t   = threadIdx.x;
  const int tx  = t & 7;     // pixel quad
  const int ty  = t >> 3;    // output quad (0..31)
  float acc[4][4] = {};      // [o_i][pix_j]
  const float* xb = x + (size_t)bn * C_IN * NPIX;
  const int k0c = ch * KCH;

  // stage all KCH=128 k rows of X (linear LDS writes — conflict-free)
  #pragma unroll
  for (int i = 0; i < 16; ++i) {
    int idx = t + i * 256;
    Xs[idx >> 5][idx & 31] = xb[(size_t)(k0c + (idx >> 5)) * NPIX + hw0 + (idx & 31)];
  }
  __syncthreads();

  const float4* wp = (const float4*)(wT + (size_t)k0c * NOP) + ty;  // 32 float4/row
  float4 wa0,wa1,wa2,wa3,wa4,wa5,wa6,wa7;
  float4 wb0,wb1,wb2,wb3,wb4,wb5,wb6,wb7;

#define LOADW(buf, base) \
  buf##0 = wp[(base+0)*32]; buf##1 = wp[(base+1)*32]; \
  buf##2 = wp[(base+2)*32]; buf##3 = wp[(base+3)*32]; \
  buf##4 = wp[(base+4)*32]; buf##5 = wp[(base+5)*32]; \
  buf##6 = wp[(base+6)*32]; buf##7 = wp[(base+7)*32];

#define FMA8(buf, kb) { \
  _Pragma("unroll") \
  for (int i = 0; i < 8; ++i) { \
    float4 xa = *(const float4*)&Xs[(kb) + i][tx*4]; \
    float4 wv = (i==0)?buf##0:(i==1)?buf##1:(i==2)?buf##2:(i==3)?buf##3: \
                (i==4)?buf##4:(i==5)?buf##5:(i==6)?buf##6:buf##7; \
    acc[0][0] += wv.x*xa.x; acc[0][1] += wv.x*xa.y; acc[0][2] += wv.x*xa.z; acc[0][3] += wv.x*xa.w; \
    acc[1][0] += wv.y*xa.x; acc[1][1] += wv.y*xa.y; acc[1][2] += wv.y*xa.z; acc[1][3] += wv.y*xa.w; \
    acc[2][0] += wv.z*xa.x; acc[2][1] += wv.z*xa.y; acc[2][2] += wv.z*xa.z; acc[2][3] += wv.z*xa.w; \
    acc[3][0] += wv.w*xa.x; acc[3][1] += wv.w*xa.y; acc[3][2] += wv.w*xa.z; acc[3][3] += wv.w*xa.w; \
  } }

  LOADW(wa, 0)
  #pragma unroll
  for (int gp = 0; gp < 8; ++gp) {      // 8 pairs of 8-k groups = 128 k
    const int kb = gp * 16;
    if (gp < 8)        { LOADW(wb, kb/8 + 1 == 16 ? 0 : (gp*2 + 1) * 8 / 8 * 8) } // placeholder
    FMA8(wa, kb)
    if (gp < 7)        { LOADW(wa, (gp*2 + 2) * 8) }
    FMA8(wb, kb + 8)
  }
#undef LOADW
#undef FMA8

  // epilogue: transpose to pixel-major via LDS, coalesced global write
  __syncthreads();
  float (*PT)[128] = (float(*)[128])smem;          // [32 pix][128 o] aligned
  #pragma unroll
  for (int j = 0; j < 4; ++j) {
    float4 v = make_float4(acc[0][j], acc[1][j], acc[2][j], acc[3][j]);
    *(float4*)&PT[tx*4 + j][ty*4] = v;
  }
  __syncthreads();
  float* dst = partial + ((size_t)(ch*NBN + bn) * NPIX + hw0) * NOP;
  #pragma unroll
  for (int p = 0; p < 4; ++p) {
    int pix = (t >> 5) + p * 8;
    int o4  = (t & 31) * 4;
    *(float4*)&dst[(size_t)pix * NOP + o4] = *(const float4*)&PT[pix][o4];
  }
}

// ---------- FUSED combine+agg: one block per (bn, col) ----------
__global__ __launch_bounds__(256) void sm_agg_kernel(
    const float* __restrict__ wsf, const float* __restrict__ trans,
    const float* __restrict__ partial, const float* __restrict__ bias,
    float* __restrict__ bev)
{
#pragma clang fp contract(off)
  __shared__ float dep_s[FH][60];   // stride 60: 2-way bank alias (free)
  __shared__ float ctx_s[FH][C_TR];
  const int blk  = blockIdx.x;
  const int bn   = blk / FW;
  const int col  = blk - bn * FW;
  const int wave = threadIdx.x >> 6;
  const int lane = threadIdx.x & 63;
  const int b    = bn / NCAM;

  #pragma unroll
  for (int rr = 0; rr < 4; ++rr) {
    const int row = wave * 4 + rr;
    const int pix = row * FW + col;
    float v0 = 0.0f, v1 = 0.0f;
    #pragma unroll
    for (int ch = 0; ch < NCH; ++ch) {
      const float* p = partial + ((size_t)(ch*NBN + bn) * NPIX + pix) * NOP;
      v0 += p[lane];
      v1 += p[lane + 64];
    }
    v0 += bias[lane];
    v1 += (lane + 64 < NO) ? bias[lane + 64] : 0.0f;

    float logit = (lane < DBINS) ? v0 : -__builtin_inff();
    float m = logit;
    #pragma unroll
    for (int off = 32; off; off >>= 1) m = fmaxf(m, __shfl_xor(m, off, 64));
    float e = (lane < DBINS) ? expf(logit - m) : 0.0f;
    float s = e;
    #pragma unroll
    for (int off = 32; off; off >>= 1) s += __shfl_xor(s, off, 64);
    if (lane < DBINS) dep_s[row][lane] = e / s;

    float a  = __shfl(v0, (DBINS + lane) & 63, 64);
    float b2 = __shfl(v1, (DBINS + lane - 64) & 63, 64);
    ctx_s[row][lane] = (lane < 5) ? a : b2;
  }
  __syncthreads();

  const float* cm = wsf + WS_CMB + bn * 9;
  const float* tr = trans + bn * 3;
  const int r = lane & 15;
  for (int dm1 = wave; dm1 < DBINS; dm1 += 4) {
    const float dd = 1.0f + (float)dm1;
    const float px = wsf[WS_XS + col] * dd;
    const float py0 = wsf[WS_YS + 0] * dd;
    const float e0 = (cm[0]*px + cm[1]*py0) + cm[2]*dd;
    const float e1 = (cm[3]*px + cm[4]*py0) + cm[5]*dd;
    const float g0 = e0 + tr[0];
    const float g1 = e1 + tr[1];
    const int gx = (int)truncf((g0 + 51.2f) / 0.8f);
    const int gy = (int)truncf((g1 + 51.2f) / 0.8f);
    if (gx < 0 || gx >= NXG || gy < 0 || gy >= NYG) continue;  // wave-uniform

    const float pyr = wsf[WS_YS + r] * dd;
    const float e2 = (cm[6]*px + cm[7]*pyr) + cm[8]*dd;
    const float g2 = e2 + tr[2];
    const int gz = (int)truncf((g2 + 10.0f) / 20.0f);
    unsigned long long mask = __ballot(gz == 0) & 0xFFFFull;
    if (mask == 0) continue;                                   // wave-uniform

    const float dep_r = dep_s[r][dm1];
    float acc = 0.0f;
    #pragma unroll
    for (int row = 0; row < FH; ++row) {
      if ((mask >> row) & 1ull) {   // wave-uniform
        float dv = __shfl(dep_r, row, 64);
        acc += dv * ctx_s[row][lane];
      }
    }
    atomicAdd(&bev[(((size_t)(b*NXG + gx) * NYG + gy) * C_TR) + lane], acc);
  }
}

__global__ __launch_bounds__(256) void transpose_kernel(
    const float* __restrict__ bev, float* __restrict__ out)
{
  __shared__ float tile[NYG][C_TR + 1];
  const int b  = blockIdx.x >> 7;
  const int gx = blockIdx.x & 127;
  const float* src = bev + ((size_t)(b * NXG + gx) * NYG) * C_TR;
  const int t = threadIdx.x;
  #pragma unroll
  for (int i = 0; i < 32; ++i) {
    int idx = t + i * 256;
    tile[idx >> 6][idx & 63] = src[idx];
  }
  __syncthreads();
  const int lane = t & 63;
  const int cw   = t >> 6;
  size_t obase = (size_t)b * (C_TR*NXG*NYG) + (size_t)gx * NYG;
  #pragma unroll
  for (int i = 0; i < 16; ++i) {
    int c = cw + i * 4;
    out[obase + (size_t)c * (NXG*NYG) + lane]      = tile[lane][c];
    out[obase + (size_t)c * (NXG*NYG) + 64 + lane] = tile[64 + lane][c];
  }
}

// ---------- FALLBACK (R8 path, proven) ----------
__global__ __launch_bounds__(256) void gemm_fb_kernel(
    const float* __restrict__ x, const float* __restrict__ w,
    const float* __restrict__ bias, float* __restrict__ feat,
    float* __restrict__ ctx_t)
{
  __shared__ float Xs[64][32];
  __shared__ float Ws[128][66];
  __shared__ float CtxT[32][C_TR];
  const int bn  = blockIdx.y;
  const int hw0 = blockIdx.x * 32;
  const int t   = threadIdx.x;
  const int tx  = t & 7;
  const int ty  = t >> 3;
  float acc[4][4] = {};
  const float* xb = x + (size_t)bn * C_IN * NPIX;

  for (int k0 = 0; k0 < C_IN; k0 += 64) {
    #pragma unroll
    for (int i = 0; i < 8; ++i) {
      int r = (t >> 5) + i * 8;
      Xs[r][t & 31] = xb[(size_t)(k0 + r) * NPIX + hw0 + (t & 31)];
    }
    #pragma unroll
    for (int i = 0; i < 32; ++i) {
      int o = (t >> 6) + i * 4;
      Ws[o][t & 63] = (o < NO) ? w[(size_t)o * C_IN + k0 + (t & 63)] : 0.0f;
    }
    __syncthreads();
    #pragma unroll 8
    for (int k = 0; k < 64; k += 2) {
      float4 xa = *(const float4*)&Xs[k][tx*4];
      float4 xc = *(const float4*)&Xs[k+1][tx*4];
      #pragma unroll
      for (int i = 0; i < 4; ++i) {
        float2 wv = *(const float2*)&Ws[ty*4+i][k];
        acc[i][0] += wv.x*xa.x; acc[i][1] += wv.x*xa.y;
        acc[i][2] += wv.x*xa.z; acc[i][3] += wv.x*xa.w;
        acc[i][0] += wv.y*xc.x; acc[i][1] += wv.y*xc.y;
        acc[i][2] += wv.y*xc.z; acc[i][3] += wv.y*xc.w;
      }
    }
    __syncthreads();
  }
  #pragma unroll
  for (int i = 0; i < 4; ++i) {
    int o = ty*4 + i;
    float bb = (o < NO) ? bias[o] : 0.0f;
    float4 v = make_float4(acc[i][0]+bb, acc[i][1]+bb, acc[i][2]+bb, acc[i][3]+bb);
    *(float4*)&feat[((size_t)bn * NOP + o) * NPIX + hw0 + tx*4] = v;
    if (o >= DBINS && o < NO) {
      int c = o - DBINS;
      CtxT[tx*4+0][c] = v.x; CtxT[tx*4+1][c] = v.y;
      CtxT[tx*4+2][c] = v.z; CtxT[tx*4+3][c] = v.w;
    }
  }
  __syncthreads();
  const float* src = &CtxT[0][0];
  float* dst = ctx_t + ((size_t)bn * NPIX + hw0) * C_TR;
  #pragma unroll
  for (int k = 0; k < 2; ++k) {
    int f = (t + 256*k) * 4;
    *(float4*)&dst[f] = *(const float4*)&src[f];
  }
}

__global__ __launch_bounds__(256) void softmax_fb_kernel(float* __restrict__ feat)
{
  const int gwid = (int)((blockIdx.x * blockDim.x + threadIdx.x) >> 6);
  const int lane = threadIdx.x & 63;
  if (gwid >= NBN * NPIX) return;
  const int bn = gwid / NPIX;
  const int hw = gwid - bn * NPIX;
  float* fb = feat + (size_t)bn * NOP * NPIX + hw;
  float logit = (lane < DBINS) ? fb[(size_t)lane * NPIX] : -__builtin_inff();
  float m = logit;
  #pragma unroll
  for (int off = 32; off; off >>= 1) m = fmaxf(m, __shfl_xor(m, off, 64));
  float e = (lane < DBINS) ? expf(logit - m) : 0.0f;
  float s = e;
  #pragma unroll
  for (int off = 32; off; off >>= 1) s += __shfl_xor(s, off, 64);
  if (lane < DBINS) fb[(size_t)lane * NPIX] = e / s;
}

__global__ __launch_bounds__(256) void agg_kernel(
    const float* __restrict__ wsf, const float* __restrict__ trans,
    const float* __restrict__ dep, const float* __restrict__ ctx,
    float* __restrict__ bev, size_t sBN, size_t sD, size_t sP)
{
#pragma clang fp contract(off)
  const int wid = (int)((blockIdx.x * blockDim.x + threadIdx.x) >> 6);
  const int lane = threadIdx.x & 63;
  if (wid >= NBN * FW * DBINS) return;
  const int bn  = wid / (FW * DBINS);
  const int rem = wid - bn * (FW * DBINS);
  const int col = rem / DBINS;
  const int dm1 = rem - col * DBINS;
  const int b   = bn / NCAM;

  const float* cm = wsf + WS_CMB + bn * 9;
  const float* tr = trans + bn * 3;
  const float dd = 1.0f + (float)dm1;
  const float px = wsf[WS_XS + col] * dd;
  const float py0 = wsf[WS_YS + 0] * dd;
  const float e0 = (cm[0]*px + cm[1]*py0) + cm[2]*dd;
  const float e1 = (cm[3]*px + cm[4]*py0) + cm[5]*dd;
  const float g0 = e0 + tr[0];
  const float g1 = e1 + tr[1];
  const int gx = (int)truncf((g0 + 51.2f) / 0.8f);
  const int gy = (int)truncf((g1 + 51.2f) / 0.8f);
  if (gx < 0 || gx >= NXG || gy < 0 || gy >= NYG) return;

  const int r = lane & 15;
  const float pyr = wsf[WS_YS + r] * dd;
  const float e2 = (cm[6]*px + cm[7]*pyr) + cm[8]*dd;
  const float g2 = e2 + tr[2];
  const int gz = (int)truncf((g2 + 10.0f) / 20.0f);
  unsigned long long mask = __ballot(gz == 0) & 0xFFFFull;
  if (mask == 0) return;

  const float dep_r = dep[(size_t)bn * sBN + (size_t)dm1 * sD + (size_t)(r*FW + col) * sP];
  const float* ctxbase = ctx + ((size_t)bn * NPIX + col) * C_TR + lane;

  float acc = 0.0f;
  #pragma unroll
  for (int row = 0; row < FH; ++row) {
    if ((mask >> row) & 1ull) {
      float dv = __shfl(dep_r, row, 64);
      acc += dv * ctxbase[(size_t)(row * FW) * C_TR];
    }
  }
  atomicAdd(&bev[(((size_t)(b*NXG + gx) * NYG + gy) * C_TR) + lane], acc);
}

extern "C" void kernel_launch(void* const* d_in, const int* in_sizes, int n_in,
                              void* d_out, int out_size, void* d_ws, size_t ws_size,
                              hipStream_t stream)
{
  const float* x       = (const float*)d_in[0];
  const float* rots    = (const float*)d_in[1];
  const float* trans   = (const float*)d_in[2];
  const float* intrins = (const float*)d_in[3];
  const float* wd      = (const float*)d_in[4];
  const float* bd      = (const float*)d_in[5];
  float* out = (float*)d_out;
  float* wsf = (float*)d_ws;

  if (ws_size >= (size_t)WS_FAST_TOTALF * sizeof(float)) {
    float* wT    = wsf + WSP_WT;
    float* part  = wsf + WSP_PART;
    float* bev   = wsf + WSP_BEV;
    zero_prep_kernel<<<2048, 256, 0, stream>>>(
        (float4*)bev, BEV_SZ/4, rots, intrins, wd, wT, wsf);
    gemm_split_kernel<<<dim3(NPIX/32, NBN, NCH), 256, 0, stream>>>(x, wT, part);
    sm_agg_kernel<<<NBN*FW, 256, 0, stream>>>(wsf, trans, part, bd, bev);
    transpose_kernel<<<NBATCH*NXG, 256, 0, stream>>>(bev, out);
  } else {
    float* feat  = wsf + WS_FEAT;
    float* ctx_t = wsf + WS_CTX;
    float* bev   = wsf + WS_BEV;
    zero_prep_kernel<<<2048, 256, 0, stream>>>(
        (float4*)bev, BEV_SZ/4, rots, intrins, wd, nullptr, wsf);
    gemm_fb_kernel<<<dim3(NPIX/32, NBN), 256, 0, stream>>>(x, wd, bd, feat, ctx_t);
    softmax_fb_kernel<<<(NBN*NPIX)/4, 256, 0, stream>>>(feat);
    agg_kernel<<<(NBN*FW*DBINS + 3)/4, 256, 0, stream>>>(
        wsf, trans, feat, ctx_t, bev,
        (size_t)NOP * NPIX, (size_t)NPIX, (size_t)1);
    transpose_kernel<<<NBATCH*NXG, 256, 0, stream>>>(bev, out);
  }
}

// Round 19
// 72.640 us; speedup vs baseline: 1.2852x; 1.0087x over previous
//
#include <hip/hip_runtime.h>
#include <cstddef>
#include <cstdint>
#include <math.h>

#define C_IN   512
#define C_TR   64
#define DBINS  59
#define NO     123   // DBINS + C_TR
#define NOP    128   // padded
#define FH     16
#define FW     44
#define NPIX   704
#define NCAM   6
#define NBATCH 2
#define NBN    12
#define NXG    128
#define NYG    128
#define NCH    4     // split-K chunks
#define KCH    (C_IN/NCH)   // 128

// ---- shared tables (both paths) ----
#define WS_CMB     0
#define WS_XS      128
#define WS_YS      176

// ---- fast path layout (floats) ----
#define WSP_WT     256
#define WT_SZ      (C_IN*NOP)
#define WSP_PART   (WSP_WT + WT_SZ)
#define PART_SZ    (NCH*NBN*NPIX*NOP)
#define WSP_BEV    (WSP_PART + PART_SZ)
#define BEV_SZ     (NBATCH*NXG*NYG*C_TR)
#define WS_FAST_TOTALF (WSP_BEV + BEV_SZ)      // ~26MB (ws=256MB, fits)

// ---- fallback (R8) layout ----
#define WS_FEAT    256
#define WS_CTX     (WS_FEAT + NBN*NOP*NPIX)
#define WS_BEV     (WS_CTX + NBN*NPIX*C_TR)

__device__ void prep_body(const float* __restrict__ rots,
                          const float* __restrict__ intrins,
                          float* __restrict__ wsf, int t)
{
#pragma clang fp contract(off)
  if (t < NBN) {
    // np.linalg.inv f32 == sgetrf + triangular solve with RECIPROCAL-MULTIPLY
    // (LAPACK pre-inverts the diagonal). 1-ulp vs Cramer-division in inv[0][2]
    // — decides voxel-boundary points (R7 evidence). DO NOT TOUCH.
    const float* K = intrins + t * 9;
    const float* R = rots + t * 9;
    float A[3][3] = {{K[0],K[1],K[2]},{K[3],K[4],K[5]},{K[6],K[7],K[8]}};
    int piv[3] = {0,1,2};
    for (int k = 0; k < 2; ++k) {
      int p = k; float mx = fabsf(A[k][k]);
      for (int r = k+1; r < 3; ++r) { float v = fabsf(A[r][k]); if (v > mx) { mx = v; p = r; } }
      if (p != k) {
        for (int j = 0; j < 3; ++j) { float tmp = A[k][j]; A[k][j] = A[p][j]; A[p][j] = tmp; }
        int ti = piv[k]; piv[k] = piv[p]; piv[p] = ti;
      }
      float rk = 1.0f / A[k][k];
      for (int r = k+1; r < 3; ++r) {
        float l = A[r][k] * rk;
        A[r][k] = l;
        for (int j = k+1; j < 3; ++j) A[r][j] = A[r][j] - l * A[k][j];
      }
    }
    float r0 = 1.0f / A[0][0], r1 = 1.0f / A[1][1], r2 = 1.0f / A[2][2];
    float inv[3][3];
    for (int j = 0; j < 3; ++j) {
      float b0 = (piv[0]==j) ? 1.0f : 0.0f;
      float b1 = (piv[1]==j) ? 1.0f : 0.0f;
      float b2 = (piv[2]==j) ? 1.0f : 0.0f;
      float y0 = b0;
      float y1 = b1 - A[1][0]*y0;
      float y2 = (b2 - A[2][0]*y0) - A[2][1]*y1;
      float x2 = y2 * r2;
      float x1 = (y1 - A[1][2]*x2) * r1;
      float x0 = ((y0 - A[0][1]*x1) - A[0][2]*x2) * r0;
      inv[0][j] = x0; inv[1][j] = x1; inv[2][j] = x2;
    }
    float* cm = wsf + WS_CMB + t * 9;
    #pragma unroll
    for (int i = 0; i < 3; ++i)
      #pragma unroll
      for (int j = 0; j < 3; ++j)
        cm[i*3+j] = (R[i*3+0]*inv[0][j] + R[i*3+1]*inv[1][j]) + R[i*3+2]*inv[2][j];
  }
  if (t < FW) wsf[WS_XS + t] = (t == FW-1) ? 703.0f : (float)((double)t * (703.0 / 43.0));
  if (t < FH) wsf[WS_YS + t] = (t == FH-1) ? 255.0f : (float)((double)t * 17.0);
}

// small prep: wT transpose (256 KB) + tables. bev zero moved into gemm.
__global__ __launch_bounds__(256) void prep_kernel(
    const float* __restrict__ rots, const float* __restrict__ intrins,
    const float* __restrict__ w, float* __restrict__ wT,
    float* __restrict__ wsf)
{
  int i = blockIdx.x * 256 + threadIdx.x;
  const int stride = gridDim.x * 256;
  if (wT) {
    for (int j = i; j < C_IN * NOP; j += stride) {
      int k = j >> 7, o = j & 127;
      wT[j] = (o < NO) ? w[(size_t)o * C_IN + k] : 0.0f;
    }
  }
  if (blockIdx.x == 0 && threadIdx.x < 64)
    prep_body(rots, intrins, wsf, threadIdx.x);
}

// fallback bev-zero (fallback path only)
__global__ __launch_bounds__(256) void zero_kernel(float4* __restrict__ p, int n4)
{
  int i = blockIdx.x * 256 + threadIdx.x;
  const int stride = gridDim.x * 256;
  for (; i < n4; i += stride) p[i] = make_float4(0.f, 0.f, 0.f, 0.f);
}

// ---------- FAST PATH split-K GEMM (+ grid-stride bev zero) ----------
__global__ __launch_bounds__(256) void gemm_split_kernel(
    const float* __restrict__ x, const float* __restrict__ wT,
    float* __restrict__ partial, float4* __restrict__ bevp)
{
  __shared__ float smem[KCH * 32];                 // 16 KB: Xs[128][32] / PT
  float (*Xs)[32] = (float(*)[32])smem;
  const int bn  = blockIdx.y;
  const int ch  = blockIdx.z;
  const int hw0 = blockIdx.x * 32;
  const int t   = threadIdx.x;
  const int tx  = t & 7;     // pixel quad
  const int ty  = t >> 3;    // output quad (0..31)
  float acc[4][4] = {};      // [o_i][pix_j]
  const float* xb = x + (size_t)bn * C_IN * NPIX;
  const int k0c = ch * KCH;

  // bev zero: grid-stride over all 1056 blocks (overlaps X staging below)
  {
    const int blid = blockIdx.x + gridDim.x * (blockIdx.y + gridDim.y * blockIdx.z);
    const int gsz  = gridDim.x * gridDim.y * gridDim.z * 256;
    for (int j = blid * 256 + t; j < BEV_SZ/4; j += gsz)
      bevp[j] = make_float4(0.f, 0.f, 0.f, 0.f);
  }

  // stage all KCH=128 k rows of X (linear LDS writes — conflict-free)
  #pragma unroll
  for (int i = 0; i < 16; ++i) {
    int idx = t + i * 256;
    Xs[idx >> 5][idx & 31] = xb[(size_t)(k0c + (idx >> 5)) * NPIX + hw0 + (idx & 31)];
  }
  __syncthreads();

  const float4* wp = (const float4*)(wT + (size_t)k0c * NOP) + ty;  // 32 float4/row
  float4 wa0,wa1,wa2,wa3,wa4,wa5,wa6,wa7;
  float4 wb0,wb1,wb2,wb3,wb4,wb5,wb6,wb7;

#define LOADW(buf, base) \
  buf##0 = wp[(base+0)*32]; buf##1 = wp[(base+1)*32]; \
  buf##2 = wp[(base+2)*32]; buf##3 = wp[(base+3)*32]; \
  buf##4 = wp[(base+4)*32]; buf##5 = wp[(base+5)*32]; \
  buf##6 = wp[(base+6)*32]; buf##7 = wp[(base+7)*32];

#define FMA8(buf, kb) { \
  _Pragma("unroll") \
  for (int i = 0; i < 8; ++i) { \
    float4 xa = *(const float4*)&Xs[(kb) + i][tx*4]; \
    float4 wv = (i==0)?buf##0:(i==1)?buf##1:(i==2)?buf##2:(i==3)?buf##3: \
                (i==4)?buf##4:(i==5)?buf##5:(i==6)?buf##6:buf##7; \
    acc[0][0] += wv.x*xa.x; acc[0][1] += wv.x*xa.y; acc[0][2] += wv.x*xa.z; acc[0][3] += wv.x*xa.w; \
    acc[1][0] += wv.y*xa.x; acc[1][1] += wv.y*xa.y; acc[1][2] += wv.y*xa.z; acc[1][3] += wv.y*xa.w; \
    acc[2][0] += wv.z*xa.x; acc[2][1] += wv.z*xa.y; acc[2][2] += wv.z*xa.z; acc[2][3] += wv.z*xa.w; \
    acc[3][0] += wv.w*xa.x; acc[3][1] += wv.w*xa.y; acc[3][2] += wv.w*xa.z; acc[3][3] += wv.w*xa.w; \
  } }

  LOADW(wa, 0)
  #pragma unroll
  for (int gp = 0; gp < 8; ++gp) {      // 8 pairs of 8-k groups = 128 k
    const int kb = gp * 16;
    LOADW(wb, (gp*2 + 1) * 8)
    FMA8(wa, kb)
    if (gp < 7) { LOADW(wa, (gp*2 + 2) * 8) }
    FMA8(wb, kb + 8)
  }
#undef LOADW
#undef FMA8

  // epilogue: transpose to pixel-major via LDS, coalesced global write
  __syncthreads();
  float (*PT)[128] = (float(*)[128])smem;          // [32 pix][128 o] aligned
  #pragma unroll
  for (int j = 0; j < 4; ++j) {
    float4 v = make_float4(acc[0][j], acc[1][j], acc[2][j], acc[3][j]);
    *(float4*)&PT[tx*4 + j][ty*4] = v;
  }
  __syncthreads();
  float* dst = partial + ((size_t)(ch*NBN + bn) * NPIX + hw0) * NOP;
  #pragma unroll
  for (int p = 0; p < 4; ++p) {
    int pix = (t >> 5) + p * 8;
    int o4  = (t & 31) * 4;
    *(float4*)&dst[(size_t)pix * NOP + o4] = *(const float4*)&PT[pix][o4];
  }
}

// ---------- FUSED combine+agg: one block per (bn, col) ----------
__global__ __launch_bounds__(256) void sm_agg_kernel(
    const float* __restrict__ wsf, const float* __restrict__ trans,
    const float* __restrict__ partial, const float* __restrict__ bias,
    float* __restrict__ bev)
{
#pragma clang fp contract(off)
  __shared__ float dep_s[FH][60];   // stride 60: 2-way bank alias (free)
  __shared__ float ctx_s[FH][C_TR];
  const int blk  = blockIdx.x;
  const int bn   = blk / FW;
  const int col  = blk - bn * FW;
  const int wave = threadIdx.x >> 6;
  const int lane = threadIdx.x & 63;
  const int b    = bn / NCAM;

  #pragma unroll
  for (int rr = 0; rr < 4; ++rr) {
    const int row = wave * 4 + rr;
    const int pix = row * FW + col;
    float v0 = 0.0f, v1 = 0.0f;
    #pragma unroll
    for (int ch = 0; ch < NCH; ++ch) {
      const float* p = partial + ((size_t)(ch*NBN + bn) * NPIX + pix) * NOP;
      v0 += p[lane];
      v1 += p[lane + 64];
    }
    v0 += bias[lane];
    v1 += (lane + 64 < NO) ? bias[lane + 64] : 0.0f;

    float logit = (lane < DBINS) ? v0 : -__builtin_inff();
    float m = logit;
    #pragma unroll
    for (int off = 32; off; off >>= 1) m = fmaxf(m, __shfl_xor(m, off, 64));
    float e = (lane < DBINS) ? expf(logit - m) : 0.0f;
    float s = e;
    #pragma unroll
    for (int off = 32; off; off >>= 1) s += __shfl_xor(s, off, 64);
    if (lane < DBINS) dep_s[row][lane] = e / s;

    float a  = __shfl(v0, (DBINS + lane) & 63, 64);
    float b2 = __shfl(v1, (DBINS + lane - 64) & 63, 64);
    ctx_s[row][lane] = (lane < 5) ? a : b2;
  }
  __syncthreads();

  const float* cm = wsf + WS_CMB + bn * 9;
  const float* tr = trans + bn * 3;
  const int r = lane & 15;
  for (int dm1 = wave; dm1 < DBINS; dm1 += 4) {
    const float dd = 1.0f + (float)dm1;
    const float px = wsf[WS_XS + col] * dd;
    const float py0 = wsf[WS_YS + 0] * dd;
    const float e0 = (cm[0]*px + cm[1]*py0) + cm[2]*dd;
    const float e1 = (cm[3]*px + cm[4]*py0) + cm[5]*dd;
    const float g0 = e0 + tr[0];
    const float g1 = e1 + tr[1];
    const int gx = (int)truncf((g0 + 51.2f) / 0.8f);
    const int gy = (int)truncf((g1 + 51.2f) / 0.8f);
    if (gx < 0 || gx >= NXG || gy < 0 || gy >= NYG) continue;  // wave-uniform

    const float pyr = wsf[WS_YS + r] * dd;
    const float e2 = (cm[6]*px + cm[7]*pyr) + cm[8]*dd;
    const float g2 = e2 + tr[2];
    const int gz = (int)truncf((g2 + 10.0f) / 20.0f);
    unsigned long long mask = __ballot(gz == 0) & 0xFFFFull;
    if (mask == 0) continue;                                   // wave-uniform

    const float dep_r = dep_s[r][dm1];
    float acc = 0.0f;
    #pragma unroll
    for (int row = 0; row < FH; ++row) {
      if ((mask >> row) & 1ull) {   // wave-uniform
        float dv = __shfl(dep_r, row, 64);
        acc += dv * ctx_s[row][lane];
      }
    }
    atomicAdd(&bev[(((size_t)(b*NXG + gx) * NYG + gy) * C_TR) + lane], acc);
  }
}

__global__ __launch_bounds__(256) void transpose_kernel(
    const float* __restrict__ bev, float* __restrict__ out)
{
  __shared__ float tile[NYG][C_TR + 1];
  const int b  = blockIdx.x >> 7;
  const int gx = blockIdx.x & 127;
  const float* src = bev + ((size_t)(b * NXG + gx) * NYG) * C_TR;
  const int t = threadIdx.x;
  #pragma unroll
  for (int i = 0; i < 32; ++i) {
    int idx = t + i * 256;
    tile[idx >> 6][idx & 63] = src[idx];
  }
  __syncthreads();
  const int lane = t & 63;
  const int cw   = t >> 6;
  size_t obase = (size_t)b * (C_TR*NXG*NYG) + (size_t)gx * NYG;
  #pragma unroll
  for (int i = 0; i < 16; ++i) {
    int c = cw + i * 4;
    out[obase + (size_t)c * (NXG*NYG) + lane]      = tile[lane][c];
    out[obase + (size_t)c * (NXG*NYG) + 64 + lane] = tile[64 + lane][c];
  }
}

// ---------- FALLBACK (R8 path, proven) ----------
__global__ __launch_bounds__(256) void gemm_fb_kernel(
    const float* __restrict__ x, const float* __restrict__ w,
    const float* __restrict__ bias, float* __restrict__ feat,
    float* __restrict__ ctx_t)
{
  __shared__ float Xs[64][32];
  __shared__ float Ws[128][66];
  __shared__ float CtxT[32][C_TR];
  const int bn  = blockIdx.y;
  const int hw0 = blockIdx.x * 32;
  const int t   = threadIdx.x;
  const int tx  = t & 7;
  const int ty  = t >> 3;
  float acc[4][4] = {};
  const float* xb = x + (size_t)bn * C_IN * NPIX;

  for (int k0 = 0; k0 < C_IN; k0 += 64) {
    #pragma unroll
    for (int i = 0; i < 8; ++i) {
      int r = (t >> 5) + i * 8;
      Xs[r][t & 31] = xb[(size_t)(k0 + r) * NPIX + hw0 + (t & 31)];
    }
    #pragma unroll
    for (int i = 0; i < 32; ++i) {
      int o = (t >> 6) + i * 4;
      Ws[o][t & 63] = (o < NO) ? w[(size_t)o * C_IN + k0 + (t & 63)] : 0.0f;
    }
    __syncthreads();
    #pragma unroll 8
    for (int k = 0; k < 64; k += 2) {
      float4 xa = *(const float4*)&Xs[k][tx*4];
      float4 xc = *(const float4*)&Xs[k+1][tx*4];
      #pragma unroll
      for (int i = 0; i < 4; ++i) {
        float2 wv = *(const float2*)&Ws[ty*4+i][k];
        acc[i][0] += wv.x*xa.x; acc[i][1] += wv.x*xa.y;
        acc[i][2] += wv.x*xa.z; acc[i][3] += wv.x*xa.w;
        acc[i][0] += wv.y*xc.x; acc[i][1] += wv.y*xc.y;
        acc[i][2] += wv.y*xc.z; acc[i][3] += wv.y*xc.w;
      }
    }
    __syncthreads();
  }
  #pragma unroll
  for (int i = 0; i < 4; ++i) {
    int o = ty*4 + i;
    float bb = (o < NO) ? bias[o] : 0.0f;
    float4 v = make_float4(acc[i][0]+bb, acc[i][1]+bb, acc[i][2]+bb, acc[i][3]+bb);
    *(float4*)&feat[((size_t)bn * NOP + o) * NPIX + hw0 + tx*4] = v;
    if (o >= DBINS && o < NO) {
      int c = o - DBINS;
      CtxT[tx*4+0][c] = v.x; CtxT[tx*4+1][c] = v.y;
      CtxT[tx*4+2][c] = v.z; CtxT[tx*4+3][c] = v.w;
    }
  }
  __syncthreads();
  const float* src = &CtxT[0][0];
  float* dst = ctx_t + ((size_t)bn * NPIX + hw0) * C_TR;
  #pragma unroll
  for (int k = 0; k < 2; ++k) {
    int f = (t + 256*k) * 4;
    *(float4*)&dst[f] = *(const float4*)&src[f];
  }
}

__global__ __launch_bounds__(256) void softmax_fb_kernel(float* __restrict__ feat)
{
  const int gwid = (int)((blockIdx.x * blockDim.x + threadIdx.x) >> 6);
  const int lane = threadIdx.x & 63;
  if (gwid >= NBN * NPIX) return;
  const int bn = gwid / NPIX;
  const int hw = gwid - bn * NPIX;
  float* fb = feat + (size_t)bn * NOP * NPIX + hw;
  float logit = (lane < DBINS) ? fb[(size_t)lane * NPIX] : -__builtin_inff();
  float m = logit;
  #pragma unroll
  for (int off = 32; off; off >>= 1) m = fmaxf(m, __shfl_xor(m, off, 64));
  float e = (lane < DBINS) ? expf(logit - m) : 0.0f;
  float s = e;
  #pragma unroll
  for (int off = 32; off; off >>= 1) s += __shfl_xor(s, off, 64);
  if (lane < DBINS) fb[(size_t)lane * NPIX] = e / s;
}

__global__ __launch_bounds__(256) void agg_kernel(
    const float* __restrict__ wsf, const float* __restrict__ trans,
    const float* __restrict__ dep, const float* __restrict__ ctx,
    float* __restrict__ bev, size_t sBN, size_t sD, size_t sP)
{
#pragma clang fp contract(off)
  const int wid = (int)((blockIdx.x * blockDim.x + threadIdx.x) >> 6);
  const int lane = threadIdx.x & 63;
  if (wid >= NBN * FW * DBINS) return;
  const int bn  = wid / (FW * DBINS);
  const int rem = wid - bn * (FW * DBINS);
  const int col = rem / DBINS;
  const int dm1 = rem - col * DBINS;
  const int b   = bn / NCAM;

  const float* cm = wsf + WS_CMB + bn * 9;
  const float* tr = trans + bn * 3;
  const float dd = 1.0f + (float)dm1;
  const float px = wsf[WS_XS + col] * dd;
  const float py0 = wsf[WS_YS + 0] * dd;
  const float e0 = (cm[0]*px + cm[1]*py0) + cm[2]*dd;
  const float e1 = (cm[3]*px + cm[4]*py0) + cm[5]*dd;
  const float g0 = e0 + tr[0];
  const float g1 = e1 + tr[1];
  const int gx = (int)truncf((g0 + 51.2f) / 0.8f);
  const int gy = (int)truncf((g1 + 51.2f) / 0.8f);
  if (gx < 0 || gx >= NXG || gy < 0 || gy >= NYG) return;

  const int r = lane & 15;
  const float pyr = wsf[WS_YS + r] * dd;
  const float e2 = (cm[6]*px + cm[7]*pyr) + cm[8]*dd;
  const float g2 = e2 + tr[2];
  const int gz = (int)truncf((g2 + 10.0f) / 20.0f);
  unsigned long long mask = __ballot(gz == 0) & 0xFFFFull;
  if (mask == 0) return;

  const float dep_r = dep[(size_t)bn * sBN + (size_t)dm1 * sD + (size_t)(r*FW + col) * sP];
  const float* ctxbase = ctx + ((size_t)bn * NPIX + col) * C_TR + lane;

  float acc = 0.0f;
  #pragma unroll
  for (int row = 0; row < FH; ++row) {
    if ((mask >> row) & 1ull) {
      float dv = __shfl(dep_r, row, 64);
      acc += dv * ctxbase[(size_t)(row * FW) * C_TR];
    }
  }
  atomicAdd(&bev[(((size_t)(b*NXG + gx) * NYG + gy) * C_TR) + lane], acc);
}

extern "C" void kernel_launch(void* const* d_in, const int* in_sizes, int n_in,
                              void* d_out, int out_size, void* d_ws, size_t ws_size,
                              hipStream_t stream)
{
  const float* x       = (const float*)d_in[0];
  const float* rots    = (const float*)d_in[1];
  const float* trans   = (const float*)d_in[2];
  const float* intrins = (const float*)d_in[3];
  const float* wd      = (const float*)d_in[4];
  const float* bd      = (const float*)d_in[5];
  float* out = (float*)d_out;
  float* wsf = (float*)d_ws;

  if (ws_size >= (size_t)WS_FAST_TOTALF * sizeof(float)) {
    float* wT    = wsf + WSP_WT;
    float* part  = wsf + WSP_PART;
    float* bev   = wsf + WSP_BEV;
    prep_kernel<<<256, 256, 0, stream>>>(rots, intrins, wd, wT, wsf);
    gemm_split_kernel<<<dim3(NPIX/32, NBN, NCH), 256, 0, stream>>>(
        x, wT, part, (float4*)bev);
    sm_agg_kernel<<<NBN*FW, 256, 0, stream>>>(wsf, trans, part, bd, bev);
    transpose_kernel<<<NBATCH*NXG, 256, 0, stream>>>(bev, out);
  } else {
    float* feat  = wsf + WS_FEAT;
    float* ctx_t = wsf + WS_CTX;
    float* bev   = wsf + WS_BEV;
    prep_kernel<<<256, 256, 0, stream>>>(rots, intrins, wd, nullptr, wsf);
    zero_kernel<<<2048, 256, 0, stream>>>((float4*)bev, BEV_SZ/4);
    gemm_fb_kernel<<<dim3(NPIX/32, NBN), 256, 0, stream>>>(x, wd, bd, feat, ctx_t);
    softmax_fb_kernel<<<(NBN*NPIX)/4, 256, 0, stream>>>(feat);
    agg_kernel<<<(NBN*FW*DBINS + 3)/4, 256, 0, stream>>>(
        wsf, trans, feat, ctx_t, bev,
        (size_t)NOP * NPIX, (size_t)NPIX, (size_t)1);
    transpose_kernel<<<NBATCH*NXG, 256, 0, stream>>>(bev, out);
  }
}